// Round 9
// baseline (28828.824 us; speedup 1.0000x reference)
//
#include <hip/hip_runtime.h>
#include <math.h>

// GRU encoder, B=64 T=2048 E=256 H=512 V=32000.
// prep   : Wcat (B-fragment-order bf16 of [Wr;Wz;Wxh]) + fused biases + lengths
// gemm_x : per T-chunk, gather emb rows (fp32->bf16) into LDS, MFMA x-projections
// scan   : persistent recurrence, 8 clusters x 32 single-wave WGs.
//          Clustering: XCC_ID roster; LOCAL mode only if roster == exactly 8x32
//          (validates both the register and balance), else DEV mode = round-8
//          protocol. LOCAL exchange: tagged 8B packets dual-published (XCD-L2
//          swap + coherence-point swap); consumers poll the local region
//          (sc0-only, XCD-L2 latency) with bounded merge fallback to the
//          device copy every 4 futile rounds -> deadlock-impossible.
// Output head tanh(h V^T + V_b) fused into last scan launch.

typedef unsigned short u16;
typedef unsigned long long u64;
typedef __attribute__((ext_vector_type(8))) short s16x8;
typedef __attribute__((ext_vector_type(4))) unsigned short u16x4;
typedef __attribute__((ext_vector_type(4))) float f32x4;
typedef __attribute__((ext_vector_type(2))) unsigned u32x2;
typedef __attribute__((ext_vector_type(4))) unsigned u32x4;

#define MFMA16(a,b,c) __builtin_amdgcn_mfma_f32_16x16x32_bf16((a),(b),(c),0,0,0)

__device__ __forceinline__ short f2bf(float f) {
  union { float f; unsigned u; } x; x.f = f;
  unsigned r = x.u + 0x7FFFu + ((x.u >> 16) & 1u);  // RNE
  return (short)(r >> 16);
}
__device__ __forceinline__ float bf2f(unsigned short u) {
  union { unsigned u; float f; } x; x.u = ((unsigned)u) << 16;
  return x.f;
}
__device__ __forceinline__ s16x8 cvt8(const float* p) {
  float4 a = *(const float4*)p;
  float4 b = *(const float4*)(p + 4);
  s16x8 r;
  r[0]=f2bf(a.x); r[1]=f2bf(a.y); r[2]=f2bf(a.z); r[3]=f2bf(a.w);
  r[4]=f2bf(b.x); r[5]=f2bf(b.y); r[6]=f2bf(b.z); r[7]=f2bf(b.w);
  return r;
}
__device__ __forceinline__ float sigm(float x){ return 1.0f/(1.0f + __expf(-x)); }
__device__ __forceinline__ float ftanh(float x){ float e = __expf(2.0f*x); return 1.0f - 2.0f/(e + 1.0f); }

// Region read: 16 16B loads covering the 16KB slot region; loads + waitcnt in
// ONE asm block (rule #18). _DEV = coherence point, _L2 = XCD-local L2.
#define POLL16_DEV(d, b0, b1, b2, b3)                                          \
  asm volatile(                                                                \
    "global_load_dwordx4 %0, %16, off sc0 sc1\n\t"                             \
    "global_load_dwordx4 %1, %16, off offset:1024 sc0 sc1\n\t"                 \
    "global_load_dwordx4 %2, %16, off offset:2048 sc0 sc1\n\t"                 \
    "global_load_dwordx4 %3, %16, off offset:3072 sc0 sc1\n\t"                 \
    "global_load_dwordx4 %4, %17, off sc0 sc1\n\t"                             \
    "global_load_dwordx4 %5, %17, off offset:1024 sc0 sc1\n\t"                 \
    "global_load_dwordx4 %6, %17, off offset:2048 sc0 sc1\n\t"                 \
    "global_load_dwordx4 %7, %17, off offset:3072 sc0 sc1\n\t"                 \
    "global_load_dwordx4 %8, %18, off sc0 sc1\n\t"                             \
    "global_load_dwordx4 %9, %18, off offset:1024 sc0 sc1\n\t"                 \
    "global_load_dwordx4 %10, %18, off offset:2048 sc0 sc1\n\t"                \
    "global_load_dwordx4 %11, %18, off offset:3072 sc0 sc1\n\t"                \
    "global_load_dwordx4 %12, %19, off sc0 sc1\n\t"                            \
    "global_load_dwordx4 %13, %19, off offset:1024 sc0 sc1\n\t"                \
    "global_load_dwordx4 %14, %19, off offset:2048 sc0 sc1\n\t"                \
    "global_load_dwordx4 %15, %19, off offset:3072 sc0 sc1\n\t"                \
    "s_waitcnt vmcnt(0)"                                                       \
    : "=&v"(d[0]),"=&v"(d[1]),"=&v"(d[2]),"=&v"(d[3]),"=&v"(d[4]),"=&v"(d[5]), \
      "=&v"(d[6]),"=&v"(d[7]),"=&v"(d[8]),"=&v"(d[9]),"=&v"(d[10]),            \
      "=&v"(d[11]),"=&v"(d[12]),"=&v"(d[13]),"=&v"(d[14]),"=&v"(d[15])         \
    : "v"(b0), "v"(b1), "v"(b2), "v"(b3) : "memory")

#define POLL16_L2(d, b0, b1, b2, b3)                                           \
  asm volatile(                                                                \
    "global_load_dwordx4 %0, %16, off sc0\n\t"                                 \
    "global_load_dwordx4 %1, %16, off offset:1024 sc0\n\t"                     \
    "global_load_dwordx4 %2, %16, off offset:2048 sc0\n\t"                     \
    "global_load_dwordx4 %3, %16, off offset:3072 sc0\n\t"                     \
    "global_load_dwordx4 %4, %17, off sc0\n\t"                                 \
    "global_load_dwordx4 %5, %17, off offset:1024 sc0\n\t"                     \
    "global_load_dwordx4 %6, %17, off offset:2048 sc0\n\t"                     \
    "global_load_dwordx4 %7, %17, off offset:3072 sc0\n\t"                     \
    "global_load_dwordx4 %8, %18, off sc0\n\t"                                 \
    "global_load_dwordx4 %9, %18, off offset:1024 sc0\n\t"                     \
    "global_load_dwordx4 %10, %18, off offset:2048 sc0\n\t"                    \
    "global_load_dwordx4 %11, %18, off offset:3072 sc0\n\t"                    \
    "global_load_dwordx4 %12, %19, off sc0\n\t"                                \
    "global_load_dwordx4 %13, %19, off offset:1024 sc0\n\t"                    \
    "global_load_dwordx4 %14, %19, off offset:2048 sc0\n\t"                    \
    "global_load_dwordx4 %15, %19, off offset:3072 sc0\n\t"                    \
    "s_waitcnt vmcnt(0)"                                                       \
    : "=&v"(d[0]),"=&v"(d[1]),"=&v"(d[2]),"=&v"(d[3]),"=&v"(d[4]),"=&v"(d[5]), \
      "=&v"(d[6]),"=&v"(d[7]),"=&v"(d[8]),"=&v"(d[9]),"=&v"(d[10]),            \
      "=&v"(d[11]),"=&v"(d[12]),"=&v"(d[13]),"=&v"(d[14]),"=&v"(d[15])         \
    : "v"(b0), "v"(b1), "v"(b2), "v"(b3) : "memory")

// 16B-contiguous coherent loads for the output-head h staging (tail only)
#define LOAD16_SC16(d, base)                                                   \
  asm volatile(                                                                \
    "global_load_dwordx4 %0, %16, off sc0 sc1\n\t"                             \
    "global_load_dwordx4 %1, %16, off offset:16 sc0 sc1\n\t"                   \
    "global_load_dwordx4 %2, %16, off offset:32 sc0 sc1\n\t"                   \
    "global_load_dwordx4 %3, %16, off offset:48 sc0 sc1\n\t"                   \
    "global_load_dwordx4 %4, %16, off offset:64 sc0 sc1\n\t"                   \
    "global_load_dwordx4 %5, %16, off offset:80 sc0 sc1\n\t"                   \
    "global_load_dwordx4 %6, %16, off offset:96 sc0 sc1\n\t"                   \
    "global_load_dwordx4 %7, %16, off offset:112 sc0 sc1\n\t"                  \
    "global_load_dwordx4 %8, %16, off offset:128 sc0 sc1\n\t"                  \
    "global_load_dwordx4 %9, %16, off offset:144 sc0 sc1\n\t"                  \
    "global_load_dwordx4 %10, %16, off offset:160 sc0 sc1\n\t"                 \
    "global_load_dwordx4 %11, %16, off offset:176 sc0 sc1\n\t"                 \
    "global_load_dwordx4 %12, %16, off offset:192 sc0 sc1\n\t"                 \
    "global_load_dwordx4 %13, %16, off offset:208 sc0 sc1\n\t"                 \
    "global_load_dwordx4 %14, %16, off offset:224 sc0 sc1\n\t"                 \
    "global_load_dwordx4 %15, %16, off offset:240 sc0 sc1\n\t"                 \
    "s_waitcnt vmcnt(0)"                                                       \
    : "=&v"(d[0]),"=&v"(d[1]),"=&v"(d[2]),"=&v"(d[3]),"=&v"(d[4]),"=&v"(d[5]), \
      "=&v"(d[6]),"=&v"(d[7]),"=&v"(d[8]),"=&v"(d[9]),"=&v"(d[10]),            \
      "=&v"(d[11]),"=&v"(d[12]),"=&v"(d[13]),"=&v"(d[14]),"=&v"(d[15])         \
    : "v"(base) : "memory")

// returning 8B swap (ack at coherence point) — tail / handoff only
__device__ __forceinline__ void swap_store8(void* p, u32x2 d) {
  u32x2 old;
  asm volatile("global_atomic_swap_x2 %0, %1, %2, off sc0 sc1\n\t"
               "s_waitcnt vmcnt(0)"
               : "=&v"(old) : "v"(p), "v"(d) : "memory");
}
// returning device-scope add (roster rank)
__device__ __forceinline__ unsigned add_ret(unsigned* p) {
  unsigned old, one = 1u;
  asm volatile("global_atomic_add %0, %1, %2, off sc0 sc1\n\t"
               "s_waitcnt vmcnt(0)"
               : "=&v"(old) : "v"(p), "v"(one) : "memory");
  return old;
}
__device__ __forceinline__ void bar_arrive(unsigned* bar, int l) {
  if (l == 0) {
    unsigned one = 1u;
    asm volatile("global_atomic_add %0, %1, off sc1" :: "v"(bar), "v"(one) : "memory");
  }
}
__device__ __forceinline__ unsigned load_dev(const unsigned* p) {
  unsigned cur;
  asm volatile("global_load_dword %0, %1, off sc0 sc1\n\t"
               "s_waitcnt vmcnt(0)"
               : "=&v"(cur) : "v"(p) : "memory");
  return cur;
}
__device__ __forceinline__ void bar_wait(const unsigned* bar, unsigned tgt) {
  while (load_dev(bar) < tgt) {}
}

// lane redistribution for publishing: lane l' sends (row=l'&7, pair q=l'>>3)
__device__ __forceinline__ u32x2 mk_pkt(int l, unsigned d0, unsigned d1, unsigned tag) {
  const int src = (((l & 7) + ((l >> 4) << 4)) << 2);
  const int p0 = __builtin_amdgcn_ds_bpermute(src, (int)d0);
  const int p1 = __builtin_amdgcn_ds_bpermute(src, (int)d1);
  u32x2 pkt;
  pkt[0] = ((l >> 3) & 1) ? (unsigned)p1 : (unsigned)p0;
  pkt[1] = tag;
  return pkt;
}
__device__ __forceinline__ u64 slot_off(int m, int l) {
  return ((u64)((l & 7)*256 + m*8 + (l >> 3))) << 3;
}
// DEV-mode publish: device swap only (fire-and-forget)
__device__ __forceinline__ void publish_dev(char* rd, int m, int l,
                                            unsigned d0, unsigned d1, unsigned tag) {
  u32x2 pkt = mk_pkt(l, d0, d1, tag);
  void* ad = rd + slot_off(m, l);
  asm volatile("global_atomic_swap_x2 %0, %1, off sc1" :: "v"(ad), "v"(pkt) : "memory");
}
// LOCAL-mode publish: XCD-L2 swap + device swap (both fire-and-forget)
__device__ __forceinline__ void publish_dual(char* rl, char* rd, int m, int l,
                                             unsigned d0, unsigned d1, unsigned tag) {
  u32x2 pkt = mk_pkt(l, d0, d1, tag);
  const u64 off = slot_off(m, l);
  void* al = rl + off;
  void* ad = rd + off;
  asm volatile("global_atomic_swap_x2 %0, %2, off\n\t"
               "global_atomic_swap_x2 %1, %2, off sc1"
               :: "v"(al), "v"(ad), "v"(pkt) : "memory");
}

// DEV-mode post-detect tagged read (usually 1 round)
__device__ __forceinline__ void read_tagged(const char* re, int l, unsigned tag,
                                            u32x4* dd) {
  const char* b = re + (l << 4);
  for (;;) {
    POLL16_DEV(dd, b, b + 4096, b + 8192, b + 12288);
    int ok = 1;
#pragma unroll
    for (int i = 0; i < 16; ++i) ok &= (int)((dd[i][1] == tag) & (dd[i][3] == tag));
    if (__all(ok)) return;
  }
}

// LOCAL-mode wait: poll XCD-L2 copy; every 4 futile rounds merge from the
// device copy (covers replay-stale lines, cross-launch XCD migration, and any
// placement surprise) -> progress guaranteed by the sc1 copies.
__device__ __forceinline__ void wait_local(const char* lre, const char* dre,
                                           int l, unsigned tag, u32x4* dd) {
  const char* lb = lre + (l << 4);
  const char* db = dre + (l << 4);
  int fut = 0;
  for (;;) {
    POLL16_L2(dd, lb, lb + 4096, lb + 8192, lb + 12288);
    int ok = 1;
#pragma unroll
    for (int i = 0; i < 16; ++i) ok &= (int)((dd[i][1] == tag) & (dd[i][3] == tag));
    if (__all(ok)) return;
    if (++fut >= 4) {
      fut = 0;
      u32x4 dv[16];
      POLL16_DEV(dv, db, db + 4096, db + 8192, db + 12288);
#pragma unroll
      for (int i = 0; i < 16; ++i) {
        if ((dd[i][1] != tag) && (dv[i][1] == tag)) { dd[i][0] = dv[i][0]; dd[i][1] = dv[i][1]; }
        if ((dd[i][3] != tag) && (dv[i][3] == tag)) { dd[i][2] = dv[i][2]; dd[i][3] = dv[i][3]; }
      }
      ok = 1;
#pragma unroll
      for (int i = 0; i < 16; ++i) ok &= (int)((dd[i][1] == tag) & (dd[i][3] == tag));
      if (__all(ok)) return;
    }
  }
}

// ---------------- prep ----------------
__global__ void prep_kernel(const int* __restrict__ X,
                            const float* __restrict__ Wr_w, const float* __restrict__ Wz_w,
                            const float* __restrict__ Wxh_w,
                            const float* __restrict__ Wr_b, const float* __restrict__ Ur_b,
                            const float* __restrict__ Wz_b, const float* __restrict__ Uz_b,
                            const float* __restrict__ Wxh_b, const float* __restrict__ Whh_b,
                            u16* __restrict__ Wcat, float* __restrict__ bias_cat,
                            int* __restrict__ lengths) {
  const int bid = blockIdx.x, tid = threadIdx.x;
  if (bid < 64) {
    __shared__ int sred[256];
    int s = 0;
    for (int i = tid; i < 2048; i += 256) s += (X[bid*2048 + i] != 0) ? 1 : 0;
    sred[tid] = s; __syncthreads();
    for (int st = 128; st > 0; st >>= 1) { if (tid < st) sred[tid] += sred[tid + st]; __syncthreads(); }
    if (tid == 0) lengths[bid] = sred[0];
  } else if (bid < 1600) {
    const int eid = (bid - 64)*256 + tid;      // < 393216
    const int e = eid & 7, lane = (eid >> 3) & 63, ks = (eid >> 9) & 7, s = eid >> 12;
    const int j = s*16 + (lane & 15);
    const int k = ks*32 + ((lane >> 4) << 3) + e;
    float v;
    if (j < 512)       v = Wr_w[j*256 + k];
    else if (j < 1024) v = Wz_w[(j-512)*256 + k];
    else               v = Wxh_w[(j-1024)*256 + k];
    Wcat[eid] = (u16)f2bf(v);
  } else {
    const int j = (bid - 1600)*256 + tid;
    if (j < 1536) {
      float v;
      if (j < 512)       v = Wr_b[j] + Ur_b[j];
      else if (j < 1024) v = Wz_b[j-512] + Uz_b[j-512];
      else               v = Wxh_b[j-1024] + Whh_b[j-1024];
      bias_cat[j] = v;
    }
  }
}

// ---------------- gemm_x ----------------
__launch_bounds__(256, 2)
__global__ void gemm_x_kernel(const int* __restrict__ X, const float* __restrict__ emb,
                              const u16* __restrict__ Wcat, const float* __restrict__ bias,
                              u16* __restrict__ xbuf, int t0) {
  __shared__ __align__(16) u16 Alds[32768];
  const int tile = blockIdx.x >> 1, jh = blockIdx.x & 1;
  const int tid = threadIdx.x;
  const int rbase = tile * 128;
#pragma unroll
  for (int c = 0; c < 16; ++c) {
    const int id = c * 256 + tid;
    const int row = id >> 5, k8 = id & 31;
    const int lr = rbase + row;
    const int b = lr & 63, t = t0 + (lr >> 6);
    int v = X[b*2048 + t];
    v = ((unsigned)v < 32000u) ? v : 0;
    s16x8 val = cvt8(emb + (long)v*256 + (k8 << 3));
    const int lane = (row & 15) | ((k8 & 3) << 4);
    const int slot = ((row >> 4)*8 + (k8 >> 2))*64 + lane;
    *(s16x8*)(&Alds[slot << 3]) = val;
  }
  __syncthreads();
  const int w = tid >> 6, l = tid & 63;
  s16x8 af[2][8];
#pragma unroll
  for (int m = 0; m < 2; ++m)
#pragma unroll
    for (int ks = 0; ks < 8; ++ks)
      af[m][ks] = *(const s16x8*)(&Alds[((((w*2+m)*8 + ks)*64) + l) << 3]);
  for (int s = jh*48; s < jh*48 + 48; ++s) {
    s16x8 bfr[8];
    const long wco = (long)s * 4096;
#pragma unroll
    for (int ks = 0; ks < 8; ++ks)
      bfr[ks] = *(const s16x8*)(Wcat + wco + ((ks*64 + l) << 3));
    f32x4 a0 = {0.f,0.f,0.f,0.f}, a1 = {0.f,0.f,0.f,0.f};
#pragma unroll
    for (int ks = 0; ks < 8; ++ks) {
      a0 = MFMA16(af[0][ks], bfr[ks], a0);
      a1 = MFMA16(af[1][ks], bfr[ks], a1);
    }
    const int j = s*16 + (l & 15);
    const float badd = bias[j];
    const int i0 = rbase + w*32 + ((l >> 4) << 2);
#pragma unroll
    for (int e = 0; e < 4; ++e) {
      xbuf[(long)(i0 + e)*1536 + j]      = (u16)f2bf(a0[e] + badd);
      xbuf[(long)(i0 + 16 + e)*1536 + j] = (u16)f2bf(a1[e] + badd);
    }
  }
}

// ---------------- scan ----------------
// 256 single-wave WGs. Cluster cl owns batch rows [8cl,8cl+8); member mem owns
// H-dims [16mem,16mem+16). LOCAL mode: cl = XCC_ID, mem = roster rank (only if
// roster == 8x32). DEV mode: cl = wg&7, mem = wg>>3 (round-8 protocol).
__launch_bounds__(64, 1)
__global__ void scan_kernel(const float* __restrict__ Ur_w, const float* __restrict__ Uz_w,
                            const float* __restrict__ Whh_w, const u16* __restrict__ xbuf,
                            const int* __restrict__ lengths, const float* __restrict__ V_w,
                            const float* __restrict__ V_b,
                            char* __restrict__ hregL, char* __restrict__ hregD,
                            char* __restrict__ rregL, char* __restrict__ rregD,
                            float* __restrict__ h_final, unsigned* __restrict__ cnt,
                            unsigned* __restrict__ rost, float* __restrict__ out,
                            int t0, int nsteps, int last, int epoch) {
  __shared__ __align__(16) u16 Wlds[24576];  // 48 KiB: [mat(3)][ks(16)][lane(64)][e(8)]
  __shared__ __align__(16) u64 HLDS[2048];   // 16 KiB: [row(16)][dim-quad(128)]
  const int wg = blockIdx.x;
  const int l = threadIdx.x;
  const int n = l & 15, kg = l >> 4;
  const bool act = (n < 8);

  // ---- roster: LOCAL iff exactly 32 WGs per XCD ----
  unsigned* R = rost + epoch*16;             // [0..7]=per-XCD count, [8]=total
  unsigned xcc;
  asm volatile("s_getreg_b32 %0, hwreg(HW_REG_XCC_ID)" : "=s"(xcc));
  xcc &= 7;
  unsigned rank = 0;
  if (l == 0) {
    rank = add_ret(R + xcc);                 // rank add acked ...
    (void)add_ret(R + 8);                    // ... then total add (ordered)
  }
  bar_wait(R + 8, 256u);
  rank = (unsigned)__shfl((int)rank, 0);
  int balanced = 1;
  for (int x = 0; x < 8; ++x) balanced &= (load_dev(R + x) == 32u);
  const int localmode = balanced;
  const int cl  = localmode ? (int)xcc  : (wg & 7);
  const int mem = localmode ? (int)rank : (wg >> 3);
  const int jb = mem * 16;
  const int nc = act ? n : 7;
  const int rowb = cl * 8;

  // stage recurrent weights to LDS (A-frag order) and zero pad rows of HLDS
  {
    const float* Ws0 = Ur_w  + (jb + n)*512 + (kg << 3);
    const float* Ws1 = Uz_w  + (jb + n)*512 + (kg << 3);
    const float* Ws2 = Whh_w + (jb + n)*512 + (kg << 3);
#pragma unroll
    for (int ks = 0; ks < 16; ++ks) {
      *(s16x8*)(&Wlds[((     ks)*64 + l) << 3]) = cvt8(Ws0 + ks*32);
      *(s16x8*)(&Wlds[((16 + ks)*64 + l) << 3]) = cvt8(Ws1 + ks*32);
      *(s16x8*)(&Wlds[((32 + ks)*64 + l) << 3]) = cvt8(Ws2 + ks*32);
    }
#pragma unroll
    for (int i = 0; i < 16; ++i) HLDS[1024 + i*64 + l] = 0;   // pad rows 8..15
  }
  const int mylen = lengths[rowb + nc];
  const u16* xp = xbuf + (rowb + nc)*1536 + jb + (kg << 2);
  u16x4 pxr = *(const u16x4*)(xp);
  u16x4 pxz = *(const u16x4*)(xp + 512);
  u16x4 pxh = *(const u16x4*)(xp + 1024);

  char* hrcL = hregL + ((u64)cl << 15);      // cluster regions (2 parities each)
  char* hrcD = hregD + ((u64)cl << 15);
  char* rrcL = rregL + ((u64)cl << 15);
  char* rrcD = rregD + ((u64)cl << 15);
  unsigned* pc = cnt + cl*16 + 8;            // DEV-mode phase counter

  float h[4];
  if (t0 == 0) {
    h[0]=0.f; h[1]=0.f; h[2]=0.f; h[3]=0.f;
  } else {
    float4 hv = *(const float4*)(h_final + (rowb + nc)*512 + jb + (kg << 2));
    h[0]=hv.x; h[1]=hv.y; h[2]=hv.z; h[3]=hv.w;
  }

  for (int tl = 0; tl < nsteps; ++tl) {
    const int t = t0 + tl;
    const int par = t & 1;
    const u64 po  = (u64)par << 14;
    const u64 po2 = (u64)(par ^ 1) << 14;
    const unsigned tagA = (unsigned)t, tagB = (unsigned)(t + 1);
    u32x4 dd[16];
    // ---- phase A: wait h(t), compute r, publish r*h, then z ----
    if (localmode) {
      wait_local(hrcL + po, hrcD + po, l, tagA, dd);
    } else {
      if (t > 0) bar_wait(pc, 32u * (2u*(unsigned)t));
      read_tagged(hrcD + po, l, tagA, dd);
    }
#pragma unroll
    for (int i = 0; i < 16; ++i)
      HLDS[(i*64 + l) ^ (((i >> 1) & 7) << 1)] = ((u64)dd[i][2] << 32) | (u64)dd[i][0];
    f32x4 ar = {0.f,0.f,0.f,0.f}, az = {0.f,0.f,0.f,0.f};
#pragma unroll
    for (int ks = 0; ks < 16; ++ks) {
      const s16x8 hb = *(const s16x8*)((const char*)HLDS +
          (((n << 10) + ks*64 + (kg << 4)) ^ ((n & 7) << 4)));
      s16x8 w0 = *(const s16x8*)(&Wlds[((     ks)*64 + l) << 3]);
      s16x8 w1 = *(const s16x8*)(&Wlds[((16 + ks)*64 + l) << 3]);
      ar = MFMA16(w0, hb, ar);
      az = MFMA16(w1, hb, az);
    }
    unsigned rd0, rd1;
    {
      unsigned short rb_[4];
#pragma unroll
      for (int e = 0; e < 4; ++e) {
        float rr = sigm(ar[e] + bf2f(pxr[e]));
        rb_[e]   = (unsigned short)f2bf(rr * h[e]);
      }
      rd0 = (unsigned)rb_[0] | ((unsigned)rb_[1] << 16);
      rd1 = (unsigned)rb_[2] | ((unsigned)rb_[3] << 16);
    }
    if (localmode) {
      publish_dual(rrcL + po, rrcD + po, mem, l, rd0, rd1, tagB);
    } else {
      publish_dev(rrcD + po, mem, l, rd0, rd1, tagB);
      bar_arrive(pc, l);
    }
    float zz[4];
#pragma unroll
    for (int e = 0; e < 4; ++e) zz[e] = sigm(az[e] + bf2f(pxz[e]));
    // prefetch next step's x while the exchange is in flight
    const int tn = (tl < nsteps-1) ? (tl + 1) : tl;
    const u16* xq = xp + (u64)tn*98304;
    u16x4 nxr = *(const u16x4*)(xq);
    u16x4 nxz = *(const u16x4*)(xq + 512);
    u16x4 nxh = *(const u16x4*)(xq + 1024);
    // ---- phase B: wait r*h, compute update, publish h(t+1) ----
    if (localmode) {
      wait_local(rrcL + po, rrcD + po, l, tagB, dd);
    } else {
      bar_wait(pc, 32u * (2u*(unsigned)t + 1u));
      read_tagged(rrcD + po, l, tagB, dd);
    }
#pragma unroll
    for (int i = 0; i < 16; ++i)
      HLDS[(i*64 + l) ^ (((i >> 1) & 7) << 1)] = ((u64)dd[i][2] << 32) | (u64)dd[i][0];
    f32x4 au = {0.f,0.f,0.f,0.f};
#pragma unroll
    for (int ks = 0; ks < 16; ++ks) {
      const s16x8 rb = *(const s16x8*)((const char*)HLDS +
          (((n << 10) + ks*64 + (kg << 4)) ^ ((n & 7) << 4)));
      s16x8 w2 = *(const s16x8*)(&Wlds[((32 + ks)*64 + l) << 3]);
      au = MFMA16(w2, rb, au);
    }
    unsigned hd0, hd1;
    {
      unsigned short hb_[4];
#pragma unroll
      for (int e = 0; e < 4; ++e) {
        float upd = ftanh(au[e] + bf2f(pxh[e]));
        float hn  = zz[e]*h[e] + (1.f - zz[e])*upd;
        h[e] = (t < mylen) ? hn : h[e];
        hb_[e] = (unsigned short)f2bf(h[e]);
      }
      hd0 = (unsigned)hb_[0] | ((unsigned)hb_[1] << 16);
      hd1 = (unsigned)hb_[2] | ((unsigned)hb_[3] << 16);
    }
    if (localmode) {
      publish_dual(hrcL + po2, hrcD + po2, mem, l, hd0, hd1, tagB);
    } else {
      publish_dev(hrcD + po2, mem, l, hd0, hd1, tagB);
      bar_arrive(pc, l);
    }
    pxr = nxr; pxz = nxz; pxh = nxh;
  }

  if (!last) {
    // cross-launch handoff: kernel end writes back L2, plain store is fine
    if (act) {
      float4 hv; hv.x = h[0]; hv.y = h[1]; hv.z = h[2]; hv.w = h[3];
      *(float4*)(h_final + (rowb + n)*512 + jb + (kg << 2)) = hv;
    }
    return;
  }
  // last launch: publish fp32 h at device coherence point, cluster barrier, head
  if (act) {
    union { float f; unsigned u; } a0, a1, a2, a3;
    a0.f = h[0]; a1.f = h[1]; a2.f = h[2]; a3.f = h[3];
    float* hp = h_final + (rowb + n)*512 + jb + (kg << 2);
    u32x2 d0; d0[0] = a0.u; d0[1] = a1.u;
    u32x2 d1; d1[0] = a2.u; d1[1] = a3.u;
    swap_store8(hp, d0);
    swap_store8(hp + 2, d1);
  }
  unsigned* bar = cnt + cl*16;
  bar_arrive(bar, l);
  bar_wait(bar, 32u);
  // stage this cluster's 8 rows of h (16 KiB fp32) into LDS via coherent loads
  {
    f32x4 st[16];
    const float* hstage = h_final + rowb*512 + l*64;
    LOAD16_SC16(st, hstage);
    float* hlds = (float*)Wlds;
#pragma unroll
    for (int k = 0; k < 16; ++k) *(f32x4*)(&hlds[l*64 + k*4]) = st[k];
  }
  // out = tanh(hT @ V^T + V_b): WG covers its 16 dims x its 8 rows
  {
    const float* hlds = (const float*)Wlds;
    const int nn = l & 7, jo = l >> 3;
    const int j1 = jb + jo, j2 = jb + 8 + jo;
    const float* hrow = hlds + nn*512;
    const float* v1 = V_w + j1*512;
    const float* v2 = V_w + j2*512;
    float a1 = 0.f, a2 = 0.f;
    for (int k = 0; k < 512; k += 4) {
      float4 hv = *(const float4*)(hrow + k);
      float4 w1 = *(const float4*)(v1 + k);
      float4 w2 = *(const float4*)(v2 + k);
      a1 += hv.x*w1.x + hv.y*w1.y + hv.z*w1.z + hv.w*w1.w;
      a2 += hv.x*w2.x + hv.y*w2.y + hv.z*w2.z + hv.w*w2.w;
    }
    out[(rowb + nn)*512 + j1] = ftanh(a1 + V_b[j1]);
    out[(rowb + nn)*512 + j2] = ftanh(a2 + V_b[j2]);
  }
}

extern "C" void kernel_launch(void* const* d_in, const int* in_sizes, int n_in,
                              void* d_out, int out_size, void* d_ws, size_t ws_size,
                              hipStream_t stream) {
  const int*   X     = (const int*)d_in[0];
  const float* emb   = (const float*)d_in[1];
  const float* Wr_w  = (const float*)d_in[2];
  const float* Wr_b  = (const float*)d_in[3];
  const float* Ur_w  = (const float*)d_in[4];
  const float* Ur_b  = (const float*)d_in[5];
  const float* Wz_w  = (const float*)d_in[6];
  const float* Wz_b  = (const float*)d_in[7];
  const float* Uz_w  = (const float*)d_in[8];
  const float* Uz_b  = (const float*)d_in[9];
  const float* Wxh_w = (const float*)d_in[10];
  const float* Wxh_b = (const float*)d_in[11];
  const float* Whh_w = (const float*)d_in[12];
  const float* Whh_b = (const float*)d_in[13];
  const float* V_w   = (const float*)d_in[14];
  const float* V_b   = (const float*)d_in[15];
  (void)in_sizes; (void)n_in; (void)out_size;

  char* ws = (char*)d_ws;
  u16*      Wcat  = (u16*)ws;                     //     786,432 B
  float*    bias  = (float*)(ws + 786432L);       //       6,144 B
  int*      len   = (int*)(ws + 792576L);         //         256 B
  float*    hfin  = (float*)(ws + 792832L);       //     131,072 B
  unsigned* cnt   = (unsigned*)(ws + 923904L);    //         512 B (tail bar + DEV cnt)
  unsigned* rost  = (unsigned*)(ws + 924416L);    //       2,048 B (32 epochs x 16)
  char*     hregL = ws + 926464L;                 //     262,144 B (8c x 2p x 16KB)
  char*     hregD = ws + 1188608L;                //     262,144 B
  char*     rregL = ws + 1450752L;                //     262,144 B
  char*     rregD = ws + 1712896L;                //     262,144 B
  u16*      xbuf  = (u16*)(ws + 1975040L);        // 402,653,184/NC B

  const long avail = (long)ws_size - 1975040L;
  int NC = 1;
  while (NC < 32 && (402653184L / NC) > avail) NC <<= 1;
  const int chunkT = 2048 / NC;

  // zero counters, roster, all exchange regions (tags restart at 0 each call)
  hipMemsetAsync(ws + 923904L, 0, 512 + 2048 + 4*262144L, stream);
  prep_kernel<<<1606, 256, 0, stream>>>(X, Wr_w, Wz_w, Wxh_w, Wr_b, Ur_b, Wz_b, Uz_b,
                                        Wxh_b, Whh_b, Wcat, bias, len);
  for (int c = 0; c < NC; ++c) {
    gemm_x_kernel<<<chunkT, 256, 0, stream>>>(X, emb, Wcat, bias, xbuf, c*chunkT);
    scan_kernel<<<256, 64, 0, stream>>>(Ur_w, Uz_w, Whh_w, xbuf, len, V_w, V_b,
                                        hregL, hregD, rregL, rregD, hfin, cnt, rost,
                                        (float*)d_out,
                                        c*chunkT, chunkT, (c == NC-1) ? 1 : 0, c);
  }
}

// Round 10
// 9639.819 us; speedup vs baseline: 2.9906x; 2.9906x over previous
//
#include <hip/hip_runtime.h>
#include <math.h>

// GRU encoder, B=64 T=2048 E=256 H=512 V=32000.
// prep   : Wcat (B-fragment-order bf16 of [Wr;Wz;Wxh]) + fused biases + lengths
// gemm_x : per T-chunk, gather emb rows (fp32->bf16) into LDS, MFMA x-projections
// scan   : persistent recurrence, 8 static clusters x 32 single-wave WGs.
//          Exchange = tagged 8B atomic packets (fire-and-forget, sc1) + 4B
//          per-cluster phase counter. NEW: near-target pre-armed read — wait
//          counter only to target-8, then tagged region-read loop (tags gate
//          correctness; read overlaps the last arrivals, hiding one CP RT).
// Output head tanh(h V^T + V_b) fused into last scan launch.

typedef unsigned short u16;
typedef unsigned long long u64;
typedef __attribute__((ext_vector_type(8))) short s16x8;
typedef __attribute__((ext_vector_type(4))) unsigned short u16x4;
typedef __attribute__((ext_vector_type(4))) float f32x4;
typedef __attribute__((ext_vector_type(2))) unsigned u32x2;
typedef __attribute__((ext_vector_type(4))) unsigned u32x4;

#define MFMA16(a,b,c) __builtin_amdgcn_mfma_f32_16x16x32_bf16((a),(b),(c),0,0,0)

__device__ __forceinline__ short f2bf(float f) {
  union { float f; unsigned u; } x; x.f = f;
  unsigned r = x.u + 0x7FFFu + ((x.u >> 16) & 1u);  // RNE
  return (short)(r >> 16);
}
__device__ __forceinline__ float bf2f(unsigned short u) {
  union { unsigned u; float f; } x; x.u = ((unsigned)u) << 16;
  return x.f;
}
__device__ __forceinline__ s16x8 cvt8(const float* p) {
  float4 a = *(const float4*)p;
  float4 b = *(const float4*)(p + 4);
  s16x8 r;
  r[0]=f2bf(a.x); r[1]=f2bf(a.y); r[2]=f2bf(a.z); r[3]=f2bf(a.w);
  r[4]=f2bf(b.x); r[5]=f2bf(b.y); r[6]=f2bf(b.z); r[7]=f2bf(b.w);
  return r;
}
__device__ __forceinline__ float sigm(float x){ return 1.0f/(1.0f + __expf(-x)); }
__device__ __forceinline__ float ftanh(float x){ float e = __expf(2.0f*x); return 1.0f - 2.0f/(e + 1.0f); }

// One region read round: 16 coherent 16B loads covering the 16KB slot region,
// loads + waitcnt in ONE asm block (rule #18).
#define POLL16(d, b0, b1, b2, b3)                                              \
  asm volatile(                                                                \
    "global_load_dwordx4 %0, %16, off sc0 sc1\n\t"                             \
    "global_load_dwordx4 %1, %16, off offset:1024 sc0 sc1\n\t"                 \
    "global_load_dwordx4 %2, %16, off offset:2048 sc0 sc1\n\t"                 \
    "global_load_dwordx4 %3, %16, off offset:3072 sc0 sc1\n\t"                 \
    "global_load_dwordx4 %4, %17, off sc0 sc1\n\t"                             \
    "global_load_dwordx4 %5, %17, off offset:1024 sc0 sc1\n\t"                 \
    "global_load_dwordx4 %6, %17, off offset:2048 sc0 sc1\n\t"                 \
    "global_load_dwordx4 %7, %17, off offset:3072 sc0 sc1\n\t"                 \
    "global_load_dwordx4 %8, %18, off sc0 sc1\n\t"                             \
    "global_load_dwordx4 %9, %18, off offset:1024 sc0 sc1\n\t"                 \
    "global_load_dwordx4 %10, %18, off offset:2048 sc0 sc1\n\t"                \
    "global_load_dwordx4 %11, %18, off offset:3072 sc0 sc1\n\t"                \
    "global_load_dwordx4 %12, %19, off sc0 sc1\n\t"                            \
    "global_load_dwordx4 %13, %19, off offset:1024 sc0 sc1\n\t"                \
    "global_load_dwordx4 %14, %19, off offset:2048 sc0 sc1\n\t"                \
    "global_load_dwordx4 %15, %19, off offset:3072 sc0 sc1\n\t"                \
    "s_waitcnt vmcnt(0)"                                                       \
    : "=&v"(d[0]),"=&v"(d[1]),"=&v"(d[2]),"=&v"(d[3]),"=&v"(d[4]),"=&v"(d[5]), \
      "=&v"(d[6]),"=&v"(d[7]),"=&v"(d[8]),"=&v"(d[9]),"=&v"(d[10]),            \
      "=&v"(d[11]),"=&v"(d[12]),"=&v"(d[13]),"=&v"(d[14]),"=&v"(d[15])         \
    : "v"(b0), "v"(b1), "v"(b2), "v"(b3) : "memory")

// 16B-contiguous coherent loads for the output-head h staging (tail only)
#define LOAD16_SC16(d, base)                                                   \
  asm volatile(                                                                \
    "global_load_dwordx4 %0, %16, off sc0 sc1\n\t"                             \
    "global_load_dwordx4 %1, %16, off offset:16 sc0 sc1\n\t"                   \
    "global_load_dwordx4 %2, %16, off offset:32 sc0 sc1\n\t"                   \
    "global_load_dwordx4 %3, %16, off offset:48 sc0 sc1\n\t"                   \
    "global_load_dwordx4 %4, %16, off offset:64 sc0 sc1\n\t"                   \
    "global_load_dwordx4 %5, %16, off offset:80 sc0 sc1\n\t"                   \
    "global_load_dwordx4 %6, %16, off offset:96 sc0 sc1\n\t"                   \
    "global_load_dwordx4 %7, %16, off offset:112 sc0 sc1\n\t"                  \
    "global_load_dwordx4 %8, %16, off offset:128 sc0 sc1\n\t"                  \
    "global_load_dwordx4 %9, %16, off offset:144 sc0 sc1\n\t"                  \
    "global_load_dwordx4 %10, %16, off offset:160 sc0 sc1\n\t"                 \
    "global_load_dwordx4 %11, %16, off offset:176 sc0 sc1\n\t"                 \
    "global_load_dwordx4 %12, %16, off offset:192 sc0 sc1\n\t"                 \
    "global_load_dwordx4 %13, %16, off offset:208 sc0 sc1\n\t"                 \
    "global_load_dwordx4 %14, %16, off offset:224 sc0 sc1\n\t"                 \
    "global_load_dwordx4 %15, %16, off offset:240 sc0 sc1\n\t"                 \
    "s_waitcnt vmcnt(0)"                                                       \
    : "=&v"(d[0]),"=&v"(d[1]),"=&v"(d[2]),"=&v"(d[3]),"=&v"(d[4]),"=&v"(d[5]), \
      "=&v"(d[6]),"=&v"(d[7]),"=&v"(d[8]),"=&v"(d[9]),"=&v"(d[10]),            \
      "=&v"(d[11]),"=&v"(d[12]),"=&v"(d[13]),"=&v"(d[14]),"=&v"(d[15])         \
    : "v"(base) : "memory")

// returning 8B swap (ack at coherence point) — tail only
__device__ __forceinline__ void swap_store8(void* p, u32x2 d) {
  u32x2 old;
  asm volatile("global_atomic_swap_x2 %0, %1, %2, off sc0 sc1\n\t"
               "s_waitcnt vmcnt(0)"
               : "=&v"(old) : "v"(p), "v"(d) : "memory");
}
__device__ __forceinline__ void bar_arrive(unsigned* bar, int l) {
  if (l == 0) {
    unsigned one = 1u;
    asm volatile("global_atomic_add %0, %1, off sc1" :: "v"(bar), "v"(one) : "memory");
  }
}
__device__ __forceinline__ void bar_wait(const unsigned* bar, unsigned tgt) {
  unsigned cur;
  do {
    asm volatile("global_load_dword %0, %1, off sc0 sc1\n\t"
                 "s_waitcnt vmcnt(0)"
                 : "=&v"(cur) : "v"(bar) : "memory");
  } while (cur < tgt);
}

// publish 4 gate values (bf16) of (row n, dims jb+kg*4..+4) held by lanes
// (n<8, kg) as tagged 8B packets: lane l' sends (row=l'&7, pair q=l'>>3).
__device__ __forceinline__ void publish(char* region, int m, int l,
                                        unsigned d0, unsigned d1, unsigned tag) {
  const int src = (((l & 7) + ((l >> 4) << 4)) << 2);   // source lane * 4
  const int p0 = __builtin_amdgcn_ds_bpermute(src, (int)d0);
  const int p1 = __builtin_amdgcn_ds_bpermute(src, (int)d1);
  u32x2 pkt;
  pkt[0] = ((l >> 3) & 1) ? (unsigned)p1 : (unsigned)p0;
  pkt[1] = tag;
  void* addr = region + (((u64)((l & 7)*256 + m*8 + (l >> 3))) << 3);
  asm volatile("global_atomic_swap_x2 %0, %1, off sc1"
               :: "v"(addr), "v"(pkt) : "memory");    // fire-and-forget
}

// tagged region read loop: usually 1-2 rounds after pre-arm; light backoff
// only if the pre-arm was very early (rare).
__device__ __forceinline__ void read_tagged(const char* re, int l, unsigned tag,
                                            u32x4* dd) {
  const char* b = re + (l << 4);
  int fut = 0;
  for (;;) {
    POLL16(dd, b, b + 4096, b + 8192, b + 12288);
    int ok = 1;
#pragma unroll
    for (int i = 0; i < 16; ++i) ok &= (int)((dd[i][1] == tag) & (dd[i][3] == tag));
    if (__all(ok)) return;
    if (++fut >= 4) __builtin_amdgcn_s_sleep(1);
  }
}

// ---------------- prep ----------------
__global__ void prep_kernel(const int* __restrict__ X,
                            const float* __restrict__ Wr_w, const float* __restrict__ Wz_w,
                            const float* __restrict__ Wxh_w,
                            const float* __restrict__ Wr_b, const float* __restrict__ Ur_b,
                            const float* __restrict__ Wz_b, const float* __restrict__ Uz_b,
                            const float* __restrict__ Wxh_b, const float* __restrict__ Whh_b,
                            u16* __restrict__ Wcat, float* __restrict__ bias_cat,
                            int* __restrict__ lengths) {
  const int bid = blockIdx.x, tid = threadIdx.x;
  if (bid < 64) {
    __shared__ int sred[256];
    int s = 0;
    for (int i = tid; i < 2048; i += 256) s += (X[bid*2048 + i] != 0) ? 1 : 0;
    sred[tid] = s; __syncthreads();
    for (int st = 128; st > 0; st >>= 1) { if (tid < st) sred[tid] += sred[tid + st]; __syncthreads(); }
    if (tid == 0) lengths[bid] = sred[0];
  } else if (bid < 1600) {
    const int eid = (bid - 64)*256 + tid;      // < 393216
    const int e = eid & 7, lane = (eid >> 3) & 63, ks = (eid >> 9) & 7, s = eid >> 12;
    const int j = s*16 + (lane & 15);
    const int k = ks*32 + ((lane >> 4) << 3) + e;
    float v;
    if (j < 512)       v = Wr_w[j*256 + k];
    else if (j < 1024) v = Wz_w[(j-512)*256 + k];
    else               v = Wxh_w[(j-1024)*256 + k];
    Wcat[eid] = (u16)f2bf(v);
  } else {
    const int j = (bid - 1600)*256 + tid;
    if (j < 1536) {
      float v;
      if (j < 512)       v = Wr_b[j] + Ur_b[j];
      else if (j < 1024) v = Wz_b[j-512] + Uz_b[j-512];
      else               v = Wxh_b[j-1024] + Whh_b[j-1024];
      bias_cat[j] = v;
    }
  }
}

// ---------------- gemm_x ----------------
__launch_bounds__(256, 2)
__global__ void gemm_x_kernel(const int* __restrict__ X, const float* __restrict__ emb,
                              const u16* __restrict__ Wcat, const float* __restrict__ bias,
                              u16* __restrict__ xbuf, int t0) {
  __shared__ __align__(16) u16 Alds[32768];
  const int tile = blockIdx.x >> 1, jh = blockIdx.x & 1;
  const int tid = threadIdx.x;
  const int rbase = tile * 128;
#pragma unroll
  for (int c = 0; c < 16; ++c) {
    const int id = c * 256 + tid;
    const int row = id >> 5, k8 = id & 31;
    const int lr = rbase + row;
    const int b = lr & 63, t = t0 + (lr >> 6);
    int v = X[b*2048 + t];
    v = ((unsigned)v < 32000u) ? v : 0;
    s16x8 val = cvt8(emb + (long)v*256 + (k8 << 3));
    const int lane = (row & 15) | ((k8 & 3) << 4);
    const int slot = ((row >> 4)*8 + (k8 >> 2))*64 + lane;
    *(s16x8*)(&Alds[slot << 3]) = val;
  }
  __syncthreads();
  const int w = tid >> 6, l = tid & 63;
  s16x8 af[2][8];
#pragma unroll
  for (int m = 0; m < 2; ++m)
#pragma unroll
    for (int ks = 0; ks < 8; ++ks)
      af[m][ks] = *(const s16x8*)(&Alds[((((w*2+m)*8 + ks)*64) + l) << 3]);
  for (int s = jh*48; s < jh*48 + 48; ++s) {
    s16x8 bfr[8];
    const long wco = (long)s * 4096;
#pragma unroll
    for (int ks = 0; ks < 8; ++ks)
      bfr[ks] = *(const s16x8*)(Wcat + wco + ((ks*64 + l) << 3));
    f32x4 a0 = {0.f,0.f,0.f,0.f}, a1 = {0.f,0.f,0.f,0.f};
#pragma unroll
    for (int ks = 0; ks < 8; ++ks) {
      a0 = MFMA16(af[0][ks], bfr[ks], a0);
      a1 = MFMA16(af[1][ks], bfr[ks], a1);
    }
    const int j = s*16 + (l & 15);
    const float badd = bias[j];
    const int i0 = rbase + w*32 + ((l >> 4) << 2);
#pragma unroll
    for (int e = 0; e < 4; ++e) {
      xbuf[(long)(i0 + e)*1536 + j]      = (u16)f2bf(a0[e] + badd);
      xbuf[(long)(i0 + 16 + e)*1536 + j] = (u16)f2bf(a1[e] + badd);
    }
  }
}

// ---------------- scan ----------------
// 256 single-wave WGs. cluster cl = blockIdx&7 owns batch rows [8cl,8cl+8);
// member mem = blockIdx>>3 owns H-dims [16mem,16mem+16). Weights in LDS.
// Exchange region per cluster per parity: 8 rows x 256 slots x 8B = 16KB.
// Detection: phase counter pre-armed at target-8, tags gate correctness.
__launch_bounds__(64, 1)
__global__ void scan_kernel(const float* __restrict__ Ur_w, const float* __restrict__ Uz_w,
                            const float* __restrict__ Whh_w, const u16* __restrict__ xbuf,
                            const int* __restrict__ lengths, const float* __restrict__ V_w,
                            const float* __restrict__ V_b, char* __restrict__ hreg,
                            char* __restrict__ rreg, float* __restrict__ h_final,
                            unsigned* __restrict__ cnt, float* __restrict__ out,
                            int t0, int nsteps, int last) {
  __shared__ __align__(16) u16 Wlds[24576];  // 48 KiB: [mat(3)][ks(16)][lane(64)][e(8)]
  __shared__ __align__(16) u64 HLDS[2048];   // 16 KiB: [row(16)][dim-quad(128)]
  const int wg = blockIdx.x;
  const int cl = wg & 7, mem = wg >> 3;
  const int l = threadIdx.x;
  const int n = l & 15, kg = l >> 4;
  const int jb = mem * 16;
  const bool act = (n < 8);
  const int nc = act ? n : 7;
  const int rowb = cl * 8;

  // stage recurrent weights to LDS (A-frag order) and zero pad rows of HLDS
  {
    const float* Ws0 = Ur_w  + (jb + n)*512 + (kg << 3);
    const float* Ws1 = Uz_w  + (jb + n)*512 + (kg << 3);
    const float* Ws2 = Whh_w + (jb + n)*512 + (kg << 3);
#pragma unroll
    for (int ks = 0; ks < 16; ++ks) {
      *(s16x8*)(&Wlds[((     ks)*64 + l) << 3]) = cvt8(Ws0 + ks*32);
      *(s16x8*)(&Wlds[((16 + ks)*64 + l) << 3]) = cvt8(Ws1 + ks*32);
      *(s16x8*)(&Wlds[((32 + ks)*64 + l) << 3]) = cvt8(Ws2 + ks*32);
    }
#pragma unroll
    for (int i = 0; i < 16; ++i) HLDS[1024 + i*64 + l] = 0;   // pad rows 8..15
  }
  const int mylen = lengths[rowb + nc];
  const u16* xp = xbuf + (rowb + nc)*1536 + jb + (kg << 2);
  u16x4 pxr = *(const u16x4*)(xp);
  u16x4 pxz = *(const u16x4*)(xp + 512);
  u16x4 pxh = *(const u16x4*)(xp + 1024);

  char* hrc = hreg + ((u64)cl << 15);        // cluster regions (2 parities each)
  char* rrc = rreg + ((u64)cl << 15);
  unsigned* pc = cnt + cl*16 + 8;            // phase counter (own dword, tail bar at +0)

  float h[4];
  if (t0 == 0) {
    h[0]=0.f; h[1]=0.f; h[2]=0.f; h[3]=0.f;
  } else {
    float4 hv = *(const float4*)(h_final + (rowb + nc)*512 + jb + (kg << 2));
    h[0]=hv.x; h[1]=hv.y; h[2]=hv.z; h[3]=hv.w;
  }

  for (int tl = 0; tl < nsteps; ++tl) {
    const int t = t0 + tl;
    const int par = t & 1;
    const u64 po  = (u64)par << 14;
    const u64 po2 = (u64)(par ^ 1) << 14;
    const unsigned tagA = (unsigned)t, tagB = (unsigned)(t + 1);
    u32x4 dd[16];
    // ---- phase A: pre-armed wait for h(t), tagged read, r-MFMA, publish ----
    if (t > 0) bar_wait(pc, 32u * (2u*(unsigned)t) - 8u);   // near-target pre-arm
    read_tagged(hrc + po, l, tagA, dd);
#pragma unroll
    for (int i = 0; i < 16; ++i)
      HLDS[(i*64 + l) ^ (((i >> 1) & 7) << 1)] = ((u64)dd[i][2] << 32) | (u64)dd[i][0];
    // r-MFMAs only, publish ASAP; z work happens while packets are in flight
    f32x4 ar = {0.f,0.f,0.f,0.f};
#pragma unroll
    for (int ks = 0; ks < 16; ++ks) {
      const s16x8 hb = *(const s16x8*)((const char*)HLDS +
          (((n << 10) + ks*64 + (kg << 4)) ^ ((n & 7) << 4)));
      s16x8 w0 = *(const s16x8*)(&Wlds[(ks*64 + l) << 3]);
      ar = MFMA16(w0, hb, ar);
    }
    unsigned rd0, rd1;
    {
      unsigned short rb_[4];
#pragma unroll
      for (int e = 0; e < 4; ++e) {
        float rr = sigm(ar[e] + bf2f(pxr[e]));
        rb_[e]   = (unsigned short)f2bf(rr * h[e]);
      }
      rd0 = (unsigned)rb_[0] | ((unsigned)rb_[1] << 16);
      rd1 = (unsigned)rb_[2] | ((unsigned)rb_[3] << 16);
    }
    publish(rrc + po, mem, l, rd0, rd1, tagB);
    bar_arrive(pc, l);
    // z-MFMAs + sigmoid while the rh exchange is in flight
    f32x4 az = {0.f,0.f,0.f,0.f};
#pragma unroll
    for (int ks = 0; ks < 16; ++ks) {
      const s16x8 hb = *(const s16x8*)((const char*)HLDS +
          (((n << 10) + ks*64 + (kg << 4)) ^ ((n & 7) << 4)));
      s16x8 w1 = *(const s16x8*)(&Wlds[((16 + ks)*64 + l) << 3]);
      az = MFMA16(w1, hb, az);
    }
    float zz[4];
#pragma unroll
    for (int e = 0; e < 4; ++e) zz[e] = sigm(az[e] + bf2f(pxz[e]));
    // prefetch next step's x
    const int tn = (tl < nsteps-1) ? (tl + 1) : tl;
    const u16* xq = xp + (u64)tn*98304;
    u16x4 nxr = *(const u16x4*)(xq);
    u16x4 nxz = *(const u16x4*)(xq + 512);
    u16x4 nxh = *(const u16x4*)(xq + 1024);
    // ---- phase B: pre-armed wait for r*h, tagged read, update, publish ----
    bar_wait(pc, 32u * (2u*(unsigned)t + 1u) - 8u);
    read_tagged(rrc + po, l, tagB, dd);
#pragma unroll
    for (int i = 0; i < 16; ++i)
      HLDS[(i*64 + l) ^ (((i >> 1) & 7) << 1)] = ((u64)dd[i][2] << 32) | (u64)dd[i][0];
    f32x4 au = {0.f,0.f,0.f,0.f};
#pragma unroll
    for (int ks = 0; ks < 16; ++ks) {
      const s16x8 rb = *(const s16x8*)((const char*)HLDS +
          (((n << 10) + ks*64 + (kg << 4)) ^ ((n & 7) << 4)));
      s16x8 w2 = *(const s16x8*)(&Wlds[((32 + ks)*64 + l) << 3]);
      au = MFMA16(w2, rb, au);
    }
    unsigned hd0, hd1;
    {
      unsigned short hb_[4];
#pragma unroll
      for (int e = 0; e < 4; ++e) {
        float upd = ftanh(au[e] + bf2f(pxh[e]));
        float hn  = zz[e]*h[e] + (1.f - zz[e])*upd;
        h[e] = (t < mylen) ? hn : h[e];
        hb_[e] = (unsigned short)f2bf(h[e]);
      }
      hd0 = (unsigned)hb_[0] | ((unsigned)hb_[1] << 16);
      hd1 = (unsigned)hb_[2] | ((unsigned)hb_[3] << 16);
    }
    publish(hrc + po2, mem, l, hd0, hd1, tagB);
    bar_arrive(pc, l);
    pxr = nxr; pxz = nxz; pxh = nxh;
  }

  if (!last) {
    // cross-launch handoff: kernel end writes back L2, plain store is fine
    if (act) {
      float4 hv; hv.x = h[0]; hv.y = h[1]; hv.z = h[2]; hv.w = h[3];
      *(float4*)(h_final + (rowb + n)*512 + jb + (kg << 2)) = hv;
    }
    return;
  }
  // last launch: publish fp32 h at device coherence point, cluster barrier, head
  if (act) {
    union { float f; unsigned u; } a0, a1, a2, a3;
    a0.f = h[0]; a1.f = h[1]; a2.f = h[2]; a3.f = h[3];
    float* hp = h_final + (rowb + n)*512 + jb + (kg << 2);
    u32x2 d0; d0[0] = a0.u; d0[1] = a1.u;
    u32x2 d1; d1[0] = a2.u; d1[1] = a3.u;
    swap_store8(hp, d0);
    swap_store8(hp + 2, d1);
  }
  unsigned* bar = cnt + cl*16;
  bar_arrive(bar, l);
  bar_wait(bar, 32u);
  // stage this cluster's 8 rows of h (16 KiB fp32) into LDS via coherent loads
  {
    f32x4 st[16];
    const float* hstage = h_final + rowb*512 + l*64;
    LOAD16_SC16(st, hstage);
    float* hlds = (float*)Wlds;
#pragma unroll
    for (int k = 0; k < 16; ++k) *(f32x4*)(&hlds[l*64 + k*4]) = st[k];
  }
  // out = tanh(hT @ V^T + V_b): WG covers its 16 dims x its 8 rows
  {
    const float* hlds = (const float*)Wlds;
    const int nn = l & 7, jo = l >> 3;
    const int j1 = jb + jo, j2 = jb + 8 + jo;
    const float* hrow = hlds + nn*512;
    const float* v1 = V_w + j1*512;
    const float* v2 = V_w + j2*512;
    float a1 = 0.f, a2 = 0.f;
    for (int k = 0; k < 512; k += 4) {
      float4 hv = *(const float4*)(hrow + k);
      float4 w1 = *(const float4*)(v1 + k);
      float4 w2 = *(const float4*)(v2 + k);
      a1 += hv.x*w1.x + hv.y*w1.y + hv.z*w1.z + hv.w*w1.w;
      a2 += hv.x*w2.x + hv.y*w2.y + hv.z*w2.z + hv.w*w2.w;
    }
    out[(rowb + nn)*512 + j1] = ftanh(a1 + V_b[j1]);
    out[(rowb + nn)*512 + j2] = ftanh(a2 + V_b[j2]);
  }
}

extern "C" void kernel_launch(void* const* d_in, const int* in_sizes, int n_in,
                              void* d_out, int out_size, void* d_ws, size_t ws_size,
                              hipStream_t stream) {
  const int*   X     = (const int*)d_in[0];
  const float* emb   = (const float*)d_in[1];
  const float* Wr_w  = (const float*)d_in[2];
  const float* Wr_b  = (const float*)d_in[3];
  const float* Ur_w  = (const float*)d_in[4];
  const float* Ur_b  = (const float*)d_in[5];
  const float* Wz_w  = (const float*)d_in[6];
  const float* Wz_b  = (const float*)d_in[7];
  const float* Uz_w  = (const float*)d_in[8];
  const float* Uz_b  = (const float*)d_in[9];
  const float* Wxh_w = (const float*)d_in[10];
  const float* Wxh_b = (const float*)d_in[11];
  const float* Whh_w = (const float*)d_in[12];
  const float* Whh_b = (const float*)d_in[13];
  const float* V_w   = (const float*)d_in[14];
  const float* V_b   = (const float*)d_in[15];
  (void)in_sizes; (void)n_in; (void)out_size;

  char* ws = (char*)d_ws;
  u16*      Wcat = (u16*)ws;                      //     786,432 B
  float*    bias = (float*)(ws + 786432L);        //       6,144 B
  int*      len  = (int*)(ws + 792576L);          //         256 B
  float*    hfin = (float*)(ws + 792832L);        //     131,072 B
  unsigned* cnt  = (unsigned*)(ws + 923904L);     //         512 B (tail bar + phase cnt)
  char*     hreg = ws + 924416L;                  //     262,144 B (8c x 2p x 16KB)
  char*     rreg = ws + 1186560L;                 //     262,144 B
  u16*      xbuf = (u16*)(ws + 1448704L);         // 402,653,184/NC B

  const long avail = (long)ws_size - 1448704L;
  int NC = 1;
  while (NC < 32 && (402653184L / NC) > avail) NC <<= 1;
  const int chunkT = 2048 / NC;

  // zero counters + exchange regions (tags restart at 0 each call)
  hipMemsetAsync(ws + 923904L, 0, 512 + 2*262144L, stream);
  prep_kernel<<<1606, 256, 0, stream>>>(X, Wr_w, Wz_w, Wxh_w, Wr_b, Ur_b, Wz_b, Uz_b,
                                        Wxh_b, Whh_b, Wcat, bias, len);
  for (int c = 0; c < NC; ++c) {
    gemm_x_kernel<<<chunkT, 256, 0, stream>>>(X, emb, Wcat, bias, xbuf, c*chunkT);
    scan_kernel<<<256, 64, 0, stream>>>(Ur_w, Uz_w, Whh_w, xbuf, len, V_w, V_b,
                                        hreg, rreg, hfin, cnt, (float*)d_out,
                                        c*chunkT, chunkT, (c == NC-1) ? 1 : 0);
  }
}

// Round 11
// 8627.478 us; speedup vs baseline: 3.3415x; 1.1173x over previous
//
#include <hip/hip_runtime.h>
#include <math.h>

// GRU encoder, B=64 T=2048 E=256 H=512 V=32000.
// prep   : Wcat (B-fragment-order bf16 of [Wr;Wz;Wxh]) + fused biases + lengths
// gemm_x : per T-chunk, gather emb rows (fp32->bf16) into LDS, MFMA x-projections
// scan   : persistent recurrence, 8 static clusters x 32 single-wave WGs.
//          Exchange = tagged 8B atomic packets (fire-and-forget, sc1) +
//          4-WAY SPLIT phase counters (members add to sub mem&3, each on its
//          own 256B-spaced cacheline -> 8-way not 32-way RMW serialization);
//          consumers poll all 4 subs in one asm block and sum. Tags gate
//          correctness; counters are advisory timing only.
// Output head tanh(h V^T + V_b) fused into last scan launch.

typedef unsigned short u16;
typedef unsigned long long u64;
typedef __attribute__((ext_vector_type(8))) short s16x8;
typedef __attribute__((ext_vector_type(4))) unsigned short u16x4;
typedef __attribute__((ext_vector_type(4))) float f32x4;
typedef __attribute__((ext_vector_type(2))) unsigned u32x2;
typedef __attribute__((ext_vector_type(4))) unsigned u32x4;

#define MFMA16(a,b,c) __builtin_amdgcn_mfma_f32_16x16x32_bf16((a),(b),(c),0,0,0)

__device__ __forceinline__ short f2bf(float f) {
  union { float f; unsigned u; } x; x.f = f;
  unsigned r = x.u + 0x7FFFu + ((x.u >> 16) & 1u);  // RNE
  return (short)(r >> 16);
}
__device__ __forceinline__ float bf2f(unsigned short u) {
  union { unsigned u; float f; } x; x.u = ((unsigned)u) << 16;
  return x.f;
}
__device__ __forceinline__ s16x8 cvt8(const float* p) {
  float4 a = *(const float4*)p;
  float4 b = *(const float4*)(p + 4);
  s16x8 r;
  r[0]=f2bf(a.x); r[1]=f2bf(a.y); r[2]=f2bf(a.z); r[3]=f2bf(a.w);
  r[4]=f2bf(b.x); r[5]=f2bf(b.y); r[6]=f2bf(b.z); r[7]=f2bf(b.w);
  return r;
}
__device__ __forceinline__ float sigm(float x){ return 1.0f/(1.0f + __expf(-x)); }
__device__ __forceinline__ float ftanh(float x){ float e = __expf(2.0f*x); return 1.0f - 2.0f/(e + 1.0f); }

// One region read round: 16 coherent 16B loads covering the 16KB slot region,
// loads + waitcnt in ONE asm block (rule #18).
#define POLL16(d, b0, b1, b2, b3)                                              \
  asm volatile(                                                                \
    "global_load_dwordx4 %0, %16, off sc0 sc1\n\t"                             \
    "global_load_dwordx4 %1, %16, off offset:1024 sc0 sc1\n\t"                 \
    "global_load_dwordx4 %2, %16, off offset:2048 sc0 sc1\n\t"                 \
    "global_load_dwordx4 %3, %16, off offset:3072 sc0 sc1\n\t"                 \
    "global_load_dwordx4 %4, %17, off sc0 sc1\n\t"                             \
    "global_load_dwordx4 %5, %17, off offset:1024 sc0 sc1\n\t"                 \
    "global_load_dwordx4 %6, %17, off offset:2048 sc0 sc1\n\t"                 \
    "global_load_dwordx4 %7, %17, off offset:3072 sc0 sc1\n\t"                 \
    "global_load_dwordx4 %8, %18, off sc0 sc1\n\t"                             \
    "global_load_dwordx4 %9, %18, off offset:1024 sc0 sc1\n\t"                 \
    "global_load_dwordx4 %10, %18, off offset:2048 sc0 sc1\n\t"                \
    "global_load_dwordx4 %11, %18, off offset:3072 sc0 sc1\n\t"                \
    "global_load_dwordx4 %12, %19, off sc0 sc1\n\t"                            \
    "global_load_dwordx4 %13, %19, off offset:1024 sc0 sc1\n\t"                \
    "global_load_dwordx4 %14, %19, off offset:2048 sc0 sc1\n\t"                \
    "global_load_dwordx4 %15, %19, off offset:3072 sc0 sc1\n\t"                \
    "s_waitcnt vmcnt(0)"                                                       \
    : "=&v"(d[0]),"=&v"(d[1]),"=&v"(d[2]),"=&v"(d[3]),"=&v"(d[4]),"=&v"(d[5]), \
      "=&v"(d[6]),"=&v"(d[7]),"=&v"(d[8]),"=&v"(d[9]),"=&v"(d[10]),            \
      "=&v"(d[11]),"=&v"(d[12]),"=&v"(d[13]),"=&v"(d[14]),"=&v"(d[15])         \
    : "v"(b0), "v"(b1), "v"(b2), "v"(b3) : "memory")

// 16B-contiguous coherent loads for the output-head h staging (tail only)
#define LOAD16_SC16(d, base)                                                   \
  asm volatile(                                                                \
    "global_load_dwordx4 %0, %16, off sc0 sc1\n\t"                             \
    "global_load_dwordx4 %1, %16, off offset:16 sc0 sc1\n\t"                   \
    "global_load_dwordx4 %2, %16, off offset:32 sc0 sc1\n\t"                   \
    "global_load_dwordx4 %3, %16, off offset:48 sc0 sc1\n\t"                   \
    "global_load_dwordx4 %4, %16, off offset:64 sc0 sc1\n\t"                   \
    "global_load_dwordx4 %5, %16, off offset:80 sc0 sc1\n\t"                   \
    "global_load_dwordx4 %6, %16, off offset:96 sc0 sc1\n\t"                   \
    "global_load_dwordx4 %7, %16, off offset:112 sc0 sc1\n\t"                  \
    "global_load_dwordx4 %8, %16, off offset:128 sc0 sc1\n\t"                  \
    "global_load_dwordx4 %9, %16, off offset:144 sc0 sc1\n\t"                  \
    "global_load_dwordx4 %10, %16, off offset:160 sc0 sc1\n\t"                 \
    "global_load_dwordx4 %11, %16, off offset:176 sc0 sc1\n\t"                 \
    "global_load_dwordx4 %12, %16, off offset:192 sc0 sc1\n\t"                 \
    "global_load_dwordx4 %13, %16, off offset:208 sc0 sc1\n\t"                 \
    "global_load_dwordx4 %14, %16, off offset:224 sc0 sc1\n\t"                 \
    "global_load_dwordx4 %15, %16, off offset:240 sc0 sc1\n\t"                 \
    "s_waitcnt vmcnt(0)"                                                       \
    : "=&v"(d[0]),"=&v"(d[1]),"=&v"(d[2]),"=&v"(d[3]),"=&v"(d[4]),"=&v"(d[5]), \
      "=&v"(d[6]),"=&v"(d[7]),"=&v"(d[8]),"=&v"(d[9]),"=&v"(d[10]),            \
      "=&v"(d[11]),"=&v"(d[12]),"=&v"(d[13]),"=&v"(d[14]),"=&v"(d[15])         \
    : "v"(base) : "memory")

// returning 8B swap (ack at coherence point) — tail only
__device__ __forceinline__ void swap_store8(void* p, u32x2 d) {
  u32x2 old;
  asm volatile("global_atomic_swap_x2 %0, %1, %2, off sc0 sc1\n\t"
               "s_waitcnt vmcnt(0)"
               : "=&v"(old) : "v"(p), "v"(d) : "memory");
}
__device__ __forceinline__ void bar_arrive(unsigned* bar, int l) {
  if (l == 0) {
    unsigned one = 1u;
    asm volatile("global_atomic_add %0, %1, off sc1" :: "v"(bar), "v"(one) : "memory");
  }
}
__device__ __forceinline__ void bar_wait(const unsigned* bar, unsigned tgt) {
  unsigned cur;
  do {
    asm volatile("global_load_dword %0, %1, off sc0 sc1\n\t"
                 "s_waitcnt vmcnt(0)"
                 : "=&v"(cur) : "v"(bar) : "memory");
  } while (cur < tgt);
}

// 4-way split counter: member m adds to sub (m&3); subs 256B apart (distinct
// cachelines/channels) -> 8-way not 32-way same-address RMW serialization.
__device__ __forceinline__ void arrive4(unsigned* base, int mem, int l) {
  if (l == 0) {
    unsigned one = 1u;
    unsigned* p = base + ((mem & 3) << 6);   // 256 B spacing
    asm volatile("global_atomic_add %0, %1, off sc1" :: "v"(p), "v"(one) : "memory");
  }
}
// poll all 4 subs in one asm block (parallel loads, ~1 RT), compare sum
__device__ __forceinline__ void wait_sum4(const unsigned* base, unsigned tgt) {
  unsigned c0, c1, c2, c3;
  for (;;) {
    asm volatile(
      "global_load_dword %0, %4, off sc0 sc1\n\t"
      "global_load_dword %1, %4, off offset:256 sc0 sc1\n\t"
      "global_load_dword %2, %4, off offset:512 sc0 sc1\n\t"
      "global_load_dword %3, %4, off offset:768 sc0 sc1\n\t"
      "s_waitcnt vmcnt(0)"
      : "=&v"(c0), "=&v"(c1), "=&v"(c2), "=&v"(c3) : "v"(base) : "memory");
    if (c0 + c1 + c2 + c3 >= tgt) return;
  }
}

// publish 4 gate values (bf16) of (row n, dims jb+kg*4..+4) held by lanes
// (n<8, kg) as tagged 8B packets: lane l' sends (row=l'&7, pair q=l'>>3).
__device__ __forceinline__ void publish(char* region, int m, int l,
                                        unsigned d0, unsigned d1, unsigned tag) {
  const int src = (((l & 7) + ((l >> 4) << 4)) << 2);   // source lane * 4
  const int p0 = __builtin_amdgcn_ds_bpermute(src, (int)d0);
  const int p1 = __builtin_amdgcn_ds_bpermute(src, (int)d1);
  u32x2 pkt;
  pkt[0] = ((l >> 3) & 1) ? (unsigned)p1 : (unsigned)p0;
  pkt[1] = tag;
  void* addr = region + (((u64)((l & 7)*256 + m*8 + (l >> 3))) << 3);
  asm volatile("global_atomic_swap_x2 %0, %1, off sc1"
               :: "v"(addr), "v"(pkt) : "memory");    // fire-and-forget
}

// post-detect tagged read: usually 1 round; retry if a packet trails its
// member's counter add (different addresses, no ordering guarantee).
__device__ __forceinline__ void read_tagged(const char* re, int l, unsigned tag,
                                            u32x4* dd) {
  const char* b = re + (l << 4);
  for (;;) {
    POLL16(dd, b, b + 4096, b + 8192, b + 12288);
    int ok = 1;
#pragma unroll
    for (int i = 0; i < 16; ++i) ok &= (int)((dd[i][1] == tag) & (dd[i][3] == tag));
    if (__all(ok)) return;
  }
}

// ---------------- prep ----------------
__global__ void prep_kernel(const int* __restrict__ X,
                            const float* __restrict__ Wr_w, const float* __restrict__ Wz_w,
                            const float* __restrict__ Wxh_w,
                            const float* __restrict__ Wr_b, const float* __restrict__ Ur_b,
                            const float* __restrict__ Wz_b, const float* __restrict__ Uz_b,
                            const float* __restrict__ Wxh_b, const float* __restrict__ Whh_b,
                            u16* __restrict__ Wcat, float* __restrict__ bias_cat,
                            int* __restrict__ lengths) {
  const int bid = blockIdx.x, tid = threadIdx.x;
  if (bid < 64) {
    __shared__ int sred[256];
    int s = 0;
    for (int i = tid; i < 2048; i += 256) s += (X[bid*2048 + i] != 0) ? 1 : 0;
    sred[tid] = s; __syncthreads();
    for (int st = 128; st > 0; st >>= 1) { if (tid < st) sred[tid] += sred[tid + st]; __syncthreads(); }
    if (tid == 0) lengths[bid] = sred[0];
  } else if (bid < 1600) {
    const int eid = (bid - 64)*256 + tid;      // < 393216
    const int e = eid & 7, lane = (eid >> 3) & 63, ks = (eid >> 9) & 7, s = eid >> 12;
    const int j = s*16 + (lane & 15);
    const int k = ks*32 + ((lane >> 4) << 3) + e;
    float v;
    if (j < 512)       v = Wr_w[j*256 + k];
    else if (j < 1024) v = Wz_w[(j-512)*256 + k];
    else               v = Wxh_w[(j-1024)*256 + k];
    Wcat[eid] = (u16)f2bf(v);
  } else {
    const int j = (bid - 1600)*256 + tid;
    if (j < 1536) {
      float v;
      if (j < 512)       v = Wr_b[j] + Ur_b[j];
      else if (j < 1024) v = Wz_b[j-512] + Uz_b[j-512];
      else               v = Wxh_b[j-1024] + Whh_b[j-1024];
      bias_cat[j] = v;
    }
  }
}

// ---------------- gemm_x ----------------
__launch_bounds__(256, 2)
__global__ void gemm_x_kernel(const int* __restrict__ X, const float* __restrict__ emb,
                              const u16* __restrict__ Wcat, const float* __restrict__ bias,
                              u16* __restrict__ xbuf, int t0) {
  __shared__ __align__(16) u16 Alds[32768];
  const int tile = blockIdx.x >> 1, jh = blockIdx.x & 1;
  const int tid = threadIdx.x;
  const int rbase = tile * 128;
#pragma unroll
  for (int c = 0; c < 16; ++c) {
    const int id = c * 256 + tid;
    const int row = id >> 5, k8 = id & 31;
    const int lr = rbase + row;
    const int b = lr & 63, t = t0 + (lr >> 6);
    int v = X[b*2048 + t];
    v = ((unsigned)v < 32000u) ? v : 0;
    s16x8 val = cvt8(emb + (long)v*256 + (k8 << 3));
    const int lane = (row & 15) | ((k8 & 3) << 4);
    const int slot = ((row >> 4)*8 + (k8 >> 2))*64 + lane;
    *(s16x8*)(&Alds[slot << 3]) = val;
  }
  __syncthreads();
  const int w = tid >> 6, l = tid & 63;
  s16x8 af[2][8];
#pragma unroll
  for (int m = 0; m < 2; ++m)
#pragma unroll
    for (int ks = 0; ks < 8; ++ks)
      af[m][ks] = *(const s16x8*)(&Alds[((((w*2+m)*8 + ks)*64) + l) << 3]);
  for (int s = jh*48; s < jh*48 + 48; ++s) {
    s16x8 bfr[8];
    const long wco = (long)s * 4096;
#pragma unroll
    for (int ks = 0; ks < 8; ++ks)
      bfr[ks] = *(const s16x8*)(Wcat + wco + ((ks*64 + l) << 3));
    f32x4 a0 = {0.f,0.f,0.f,0.f}, a1 = {0.f,0.f,0.f,0.f};
#pragma unroll
    for (int ks = 0; ks < 8; ++ks) {
      a0 = MFMA16(af[0][ks], bfr[ks], a0);
      a1 = MFMA16(af[1][ks], bfr[ks], a1);
    }
    const int j = s*16 + (l & 15);
    const float badd = bias[j];
    const int i0 = rbase + w*32 + ((l >> 4) << 2);
#pragma unroll
    for (int e = 0; e < 4; ++e) {
      xbuf[(long)(i0 + e)*1536 + j]      = (u16)f2bf(a0[e] + badd);
      xbuf[(long)(i0 + 16 + e)*1536 + j] = (u16)f2bf(a1[e] + badd);
    }
  }
}

// ---------------- scan ----------------
// 256 single-wave WGs. cluster cl = blockIdx&7 owns batch rows [8cl,8cl+8);
// member mem = blockIdx>>3 owns H-dims [16mem,16mem+16). Weights in LDS.
// Exchange region per cluster per parity: 8 rows x 256 slots x 8B = 16KB.
// Detection: 4-way split phase counters (advisory), tags gate correctness.
__launch_bounds__(64, 1)
__global__ void scan_kernel(const float* __restrict__ Ur_w, const float* __restrict__ Uz_w,
                            const float* __restrict__ Whh_w, const u16* __restrict__ xbuf,
                            const int* __restrict__ lengths, const float* __restrict__ V_w,
                            const float* __restrict__ V_b, char* __restrict__ hreg,
                            char* __restrict__ rreg, float* __restrict__ h_final,
                            unsigned* __restrict__ cnt, unsigned* __restrict__ pcnt,
                            float* __restrict__ out,
                            int t0, int nsteps, int last) {
  __shared__ __align__(16) u16 Wlds[24576];  // 48 KiB: [mat(3)][ks(16)][lane(64)][e(8)]
  __shared__ __align__(16) u64 HLDS[2048];   // 16 KiB: [row(16)][dim-quad(128)]
  const int wg = blockIdx.x;
  const int cl = wg & 7, mem = wg >> 3;
  const int l = threadIdx.x;
  const int n = l & 15, kg = l >> 4;
  const int jb = mem * 16;
  const bool act = (n < 8);
  const int nc = act ? n : 7;
  const int rowb = cl * 8;

  // stage recurrent weights to LDS (A-frag order) and zero pad rows of HLDS
  {
    const float* Ws0 = Ur_w  + (jb + n)*512 + (kg << 3);
    const float* Ws1 = Uz_w  + (jb + n)*512 + (kg << 3);
    const float* Ws2 = Whh_w + (jb + n)*512 + (kg << 3);
#pragma unroll
    for (int ks = 0; ks < 16; ++ks) {
      *(s16x8*)(&Wlds[((     ks)*64 + l) << 3]) = cvt8(Ws0 + ks*32);
      *(s16x8*)(&Wlds[((16 + ks)*64 + l) << 3]) = cvt8(Ws1 + ks*32);
      *(s16x8*)(&Wlds[((32 + ks)*64 + l) << 3]) = cvt8(Ws2 + ks*32);
    }
#pragma unroll
    for (int i = 0; i < 16; ++i) HLDS[1024 + i*64 + l] = 0;   // pad rows 8..15
  }
  const int mylen = lengths[rowb + nc];
  const u16* xp = xbuf + (rowb + nc)*1536 + jb + (kg << 2);
  u16x4 pxr = *(const u16x4*)(xp);
  u16x4 pxz = *(const u16x4*)(xp + 512);
  u16x4 pxh = *(const u16x4*)(xp + 1024);

  char* hrc = hreg + ((u64)cl << 15);        // cluster regions (2 parities each)
  char* rrc = rreg + ((u64)cl << 15);
  unsigned* pc = pcnt + cl*256;              // 4 subs @ 256B spacing (1 KB/cluster)

  float h[4];
  if (t0 == 0) {
    h[0]=0.f; h[1]=0.f; h[2]=0.f; h[3]=0.f;
  } else {
    float4 hv = *(const float4*)(h_final + (rowb + nc)*512 + jb + (kg << 2));
    h[0]=hv.x; h[1]=hv.y; h[2]=hv.z; h[3]=hv.w;
  }

  for (int tl = 0; tl < nsteps; ++tl) {
    const int t = t0 + tl;
    const int par = t & 1;
    const u64 po  = (u64)par << 14;
    const u64 po2 = (u64)(par ^ 1) << 14;
    const unsigned tagA = (unsigned)t, tagB = (unsigned)(t + 1);
    u32x4 dd[16];
    // ---- phase A: wait h(t) (split counters), read tagged, r, publish r*h ----
    if (t > 0) wait_sum4(pc, 32u * (2u*(unsigned)t));   // t=0: h(0) pre-zeroed, tag 0
    read_tagged(hrc + po, l, tagA, dd);
#pragma unroll
    for (int i = 0; i < 16; ++i)
      HLDS[(i*64 + l) ^ (((i >> 1) & 7) << 1)] = ((u64)dd[i][2] << 32) | (u64)dd[i][0];
    f32x4 ar = {0.f,0.f,0.f,0.f}, az = {0.f,0.f,0.f,0.f};
#pragma unroll
    for (int ks = 0; ks < 16; ++ks) {
      const s16x8 hb = *(const s16x8*)((const char*)HLDS +
          (((n << 10) + ks*64 + (kg << 4)) ^ ((n & 7) << 4)));
      s16x8 w0 = *(const s16x8*)(&Wlds[((     ks)*64 + l) << 3]);
      s16x8 w1 = *(const s16x8*)(&Wlds[((16 + ks)*64 + l) << 3]);
      ar = MFMA16(w0, hb, ar);
      az = MFMA16(w1, hb, az);
    }
    // r first -> publish ASAP (z finished while packets are in flight)
    unsigned rd0, rd1;
    {
      unsigned short rb_[4];
#pragma unroll
      for (int e = 0; e < 4; ++e) {
        float rr = sigm(ar[e] + bf2f(pxr[e]));
        rb_[e]   = (unsigned short)f2bf(rr * h[e]);
      }
      rd0 = (unsigned)rb_[0] | ((unsigned)rb_[1] << 16);
      rd1 = (unsigned)rb_[2] | ((unsigned)rb_[3] << 16);
    }
    publish(rrc + po, mem, l, rd0, rd1, tagB);
    arrive4(pc, mem, l);
    float zz[4];
#pragma unroll
    for (int e = 0; e < 4; ++e) zz[e] = sigm(az[e] + bf2f(pxz[e]));
    // prefetch next step's x while the exchange is in flight
    const int tn = (tl < nsteps-1) ? (tl + 1) : tl;
    const u16* xq = xp + (u64)tn*98304;
    u16x4 nxr = *(const u16x4*)(xq);
    u16x4 nxz = *(const u16x4*)(xq + 512);
    u16x4 nxh = *(const u16x4*)(xq + 1024);
    // ---- phase B: wait r*h (split counters), read tagged, update, publish ----
    wait_sum4(pc, 32u * (2u*(unsigned)t + 1u));
    read_tagged(rrc + po, l, tagB, dd);
#pragma unroll
    for (int i = 0; i < 16; ++i)
      HLDS[(i*64 + l) ^ (((i >> 1) & 7) << 1)] = ((u64)dd[i][2] << 32) | (u64)dd[i][0];
    f32x4 au = {0.f,0.f,0.f,0.f};
#pragma unroll
    for (int ks = 0; ks < 16; ++ks) {
      const s16x8 rb = *(const s16x8*)((const char*)HLDS +
          (((n << 10) + ks*64 + (kg << 4)) ^ ((n & 7) << 4)));
      s16x8 w2 = *(const s16x8*)(&Wlds[((32 + ks)*64 + l) << 3]);
      au = MFMA16(w2, rb, au);
    }
    unsigned hd0, hd1;
    {
      unsigned short hb_[4];
#pragma unroll
      for (int e = 0; e < 4; ++e) {
        float upd = ftanh(au[e] + bf2f(pxh[e]));
        float hn  = zz[e]*h[e] + (1.f - zz[e])*upd;
        h[e] = (t < mylen) ? hn : h[e];
        hb_[e] = (unsigned short)f2bf(h[e]);
      }
      hd0 = (unsigned)hb_[0] | ((unsigned)hb_[1] << 16);
      hd1 = (unsigned)hb_[2] | ((unsigned)hb_[3] << 16);
    }
    publish(hrc + po2, mem, l, hd0, hd1, tagB);
    arrive4(pc, mem, l);
    pxr = nxr; pxz = nxz; pxh = nxh;
  }

  if (!last) {
    // cross-launch handoff: kernel end writes back L2, plain store is fine
    if (act) {
      float4 hv; hv.x = h[0]; hv.y = h[1]; hv.z = h[2]; hv.w = h[3];
      *(float4*)(h_final + (rowb + n)*512 + jb + (kg << 2)) = hv;
    }
    return;
  }
  // last launch: publish fp32 h at device coherence point, cluster barrier, head
  if (act) {
    union { float f; unsigned u; } a0, a1, a2, a3;
    a0.f = h[0]; a1.f = h[1]; a2.f = h[2]; a3.f = h[3];
    float* hp = h_final + (rowb + n)*512 + jb + (kg << 2);
    u32x2 d0; d0[0] = a0.u; d0[1] = a1.u;
    u32x2 d1; d1[0] = a2.u; d1[1] = a3.u;
    swap_store8(hp, d0);
    swap_store8(hp + 2, d1);
  }
  unsigned* bar = cnt + cl*16;
  bar_arrive(bar, l);
  bar_wait(bar, 32u);
  // stage this cluster's 8 rows of h (16 KiB fp32) into LDS via coherent loads
  {
    f32x4 st[16];
    const float* hstage = h_final + rowb*512 + l*64;
    LOAD16_SC16(st, hstage);
    float* hlds = (float*)Wlds;
#pragma unroll
    for (int k = 0; k < 16; ++k) *(f32x4*)(&hlds[l*64 + k*4]) = st[k];
  }
  // out = tanh(hT @ V^T + V_b): WG covers its 16 dims x its 8 rows
  {
    const float* hlds = (const float*)Wlds;
    const int nn = l & 7, jo = l >> 3;
    const int j1 = jb + jo, j2 = jb + 8 + jo;
    const float* hrow = hlds + nn*512;
    const float* v1 = V_w + j1*512;
    const float* v2 = V_w + j2*512;
    float a1 = 0.f, a2 = 0.f;
    for (int k = 0; k < 512; k += 4) {
      float4 hv = *(const float4*)(hrow + k);
      float4 w1 = *(const float4*)(v1 + k);
      float4 w2 = *(const float4*)(v2 + k);
      a1 += hv.x*w1.x + hv.y*w1.y + hv.z*w1.z + hv.w*w1.w;
      a2 += hv.x*w2.x + hv.y*w2.y + hv.z*w2.z + hv.w*w2.w;
    }
    out[(rowb + nn)*512 + j1] = ftanh(a1 + V_b[j1]);
    out[(rowb + nn)*512 + j2] = ftanh(a2 + V_b[j2]);
  }
}

extern "C" void kernel_launch(void* const* d_in, const int* in_sizes, int n_in,
                              void* d_out, int out_size, void* d_ws, size_t ws_size,
                              hipStream_t stream) {
  const int*   X     = (const int*)d_in[0];
  const float* emb   = (const float*)d_in[1];
  const float* Wr_w  = (const float*)d_in[2];
  const float* Wr_b  = (const float*)d_in[3];
  const float* Ur_w  = (const float*)d_in[4];
  const float* Ur_b  = (const float*)d_in[5];
  const float* Wz_w  = (const float*)d_in[6];
  const float* Wz_b  = (const float*)d_in[7];
  const float* Uz_w  = (const float*)d_in[8];
  const float* Uz_b  = (const float*)d_in[9];
  const float* Wxh_w = (const float*)d_in[10];
  const float* Wxh_b = (const float*)d_in[11];
  const float* Whh_w = (const float*)d_in[12];
  const float* Whh_b = (const float*)d_in[13];
  const float* V_w   = (const float*)d_in[14];
  const float* V_b   = (const float*)d_in[15];
  (void)in_sizes; (void)n_in; (void)out_size;

  char* ws = (char*)d_ws;
  u16*      Wcat = (u16*)ws;                      //     786,432 B
  float*    bias = (float*)(ws + 786432L);        //       6,144 B
  int*      len  = (int*)(ws + 792576L);          //         256 B
  float*    hfin = (float*)(ws + 792832L);        //     131,072 B
  unsigned* cnt  = (unsigned*)(ws + 923904L);     //         512 B (tail barrier)
  unsigned* pcnt = (unsigned*)(ws + 924416L);     //       8,192 B (8c x 4 subs @256B)
  char*     hreg = ws + 932608L;                  //     262,144 B (8c x 2p x 16KB)
  char*     rreg = ws + 1194752L;                 //     262,144 B
  u16*      xbuf = (u16*)(ws + 1456896L);         // 402,653,184/NC B

  const long avail = (long)ws_size - 1456896L;
  int NC = 1;
  while (NC < 32 && (402653184L / NC) > avail) NC <<= 1;
  const int chunkT = 2048 / NC;

  // zero counters + exchange regions (tags restart at 0 each call)
  hipMemsetAsync(ws + 923904L, 0, 512 + 8192 + 2*262144L, stream);
  prep_kernel<<<1606, 256, 0, stream>>>(X, Wr_w, Wz_w, Wxh_w, Wr_b, Ur_b, Wz_b, Uz_b,
                                        Wxh_b, Whh_b, Wcat, bias, len);
  for (int c = 0; c < NC; ++c) {
    gemm_x_kernel<<<chunkT, 256, 0, stream>>>(X, emb, Wcat, bias, xbuf, c*chunkT);
    scan_kernel<<<256, 64, 0, stream>>>(Ur_w, Uz_w, Whh_w, xbuf, len, V_w, V_b,
                                        hreg, rreg, hfin, cnt, pcnt, (float*)d_out,
                                        c*chunkT, chunkT, (c == NC-1) ? 1 : 0);
  }
}

// Round 12
// 8584.042 us; speedup vs baseline: 3.3584x; 1.0051x over previous
//
#include <hip/hip_runtime.h>
#include <math.h>

// GRU encoder, B=64 T=2048 E=256 H=512 V=32000.
// prep   : Wcat (B-fragment-order bf16 of [Wr;Wz;Wxh]) + fused biases + lengths
// gemm_x : per T-chunk, gather emb rows (fp32->bf16) into LDS, MFMA x-projections
// scan   : persistent recurrence, 8 static clusters x 32 single-wave WGs.
//          Exchange = tagged 8B atomic packets (fire-and-forget, sc1) +
//          PER-MEMBER FLAG SLOTS (member swaps its monotonic phase generation
//          into a private 64B-spaced dword -> zero RMW contention); consumers
//          detect via 32 parallel dword loads (1/lane). Tags gate correctness;
//          flags are advisory timing only.
// Output head tanh(h V^T + V_b) fused into last scan launch.

typedef unsigned short u16;
typedef unsigned long long u64;
typedef __attribute__((ext_vector_type(8))) short s16x8;
typedef __attribute__((ext_vector_type(4))) unsigned short u16x4;
typedef __attribute__((ext_vector_type(4))) float f32x4;
typedef __attribute__((ext_vector_type(2))) unsigned u32x2;
typedef __attribute__((ext_vector_type(4))) unsigned u32x4;

#define MFMA16(a,b,c) __builtin_amdgcn_mfma_f32_16x16x32_bf16((a),(b),(c),0,0,0)

__device__ __forceinline__ short f2bf(float f) {
  union { float f; unsigned u; } x; x.f = f;
  unsigned r = x.u + 0x7FFFu + ((x.u >> 16) & 1u);  // RNE
  return (short)(r >> 16);
}
__device__ __forceinline__ float bf2f(unsigned short u) {
  union { unsigned u; float f; } x; x.u = ((unsigned)u) << 16;
  return x.f;
}
__device__ __forceinline__ s16x8 cvt8(const float* p) {
  float4 a = *(const float4*)p;
  float4 b = *(const float4*)(p + 4);
  s16x8 r;
  r[0]=f2bf(a.x); r[1]=f2bf(a.y); r[2]=f2bf(a.z); r[3]=f2bf(a.w);
  r[4]=f2bf(b.x); r[5]=f2bf(b.y); r[6]=f2bf(b.z); r[7]=f2bf(b.w);
  return r;
}
__device__ __forceinline__ float sigm(float x){ return 1.0f/(1.0f + __expf(-x)); }
__device__ __forceinline__ float ftanh(float x){ float e = __expf(2.0f*x); return 1.0f - 2.0f/(e + 1.0f); }

// One region read round: 16 coherent 16B loads covering the 16KB slot region,
// loads + waitcnt in ONE asm block (rule #18).
#define POLL16(d, b0, b1, b2, b3)                                              \
  asm volatile(                                                                \
    "global_load_dwordx4 %0, %16, off sc0 sc1\n\t"                             \
    "global_load_dwordx4 %1, %16, off offset:1024 sc0 sc1\n\t"                 \
    "global_load_dwordx4 %2, %16, off offset:2048 sc0 sc1\n\t"                 \
    "global_load_dwordx4 %3, %16, off offset:3072 sc0 sc1\n\t"                 \
    "global_load_dwordx4 %4, %17, off sc0 sc1\n\t"                             \
    "global_load_dwordx4 %5, %17, off offset:1024 sc0 sc1\n\t"                 \
    "global_load_dwordx4 %6, %17, off offset:2048 sc0 sc1\n\t"                 \
    "global_load_dwordx4 %7, %17, off offset:3072 sc0 sc1\n\t"                 \
    "global_load_dwordx4 %8, %18, off sc0 sc1\n\t"                             \
    "global_load_dwordx4 %9, %18, off offset:1024 sc0 sc1\n\t"                 \
    "global_load_dwordx4 %10, %18, off offset:2048 sc0 sc1\n\t"                \
    "global_load_dwordx4 %11, %18, off offset:3072 sc0 sc1\n\t"                \
    "global_load_dwordx4 %12, %19, off sc0 sc1\n\t"                            \
    "global_load_dwordx4 %13, %19, off offset:1024 sc0 sc1\n\t"                \
    "global_load_dwordx4 %14, %19, off offset:2048 sc0 sc1\n\t"                \
    "global_load_dwordx4 %15, %19, off offset:3072 sc0 sc1\n\t"                \
    "s_waitcnt vmcnt(0)"                                                       \
    : "=&v"(d[0]),"=&v"(d[1]),"=&v"(d[2]),"=&v"(d[3]),"=&v"(d[4]),"=&v"(d[5]), \
      "=&v"(d[6]),"=&v"(d[7]),"=&v"(d[8]),"=&v"(d[9]),"=&v"(d[10]),            \
      "=&v"(d[11]),"=&v"(d[12]),"=&v"(d[13]),"=&v"(d[14]),"=&v"(d[15])         \
    : "v"(b0), "v"(b1), "v"(b2), "v"(b3) : "memory")

// 16B-contiguous coherent loads for the output-head h staging (tail only)
#define LOAD16_SC16(d, base)                                                   \
  asm volatile(                                                                \
    "global_load_dwordx4 %0, %16, off sc0 sc1\n\t"                             \
    "global_load_dwordx4 %1, %16, off offset:16 sc0 sc1\n\t"                   \
    "global_load_dwordx4 %2, %16, off offset:32 sc0 sc1\n\t"                   \
    "global_load_dwordx4 %3, %16, off offset:48 sc0 sc1\n\t"                   \
    "global_load_dwordx4 %4, %16, off offset:64 sc0 sc1\n\t"                   \
    "global_load_dwordx4 %5, %16, off offset:80 sc0 sc1\n\t"                   \
    "global_load_dwordx4 %6, %16, off offset:96 sc0 sc1\n\t"                   \
    "global_load_dwordx4 %7, %16, off offset:112 sc0 sc1\n\t"                  \
    "global_load_dwordx4 %8, %16, off offset:128 sc0 sc1\n\t"                  \
    "global_load_dwordx4 %9, %16, off offset:144 sc0 sc1\n\t"                  \
    "global_load_dwordx4 %10, %16, off offset:160 sc0 sc1\n\t"                 \
    "global_load_dwordx4 %11, %16, off offset:176 sc0 sc1\n\t"                 \
    "global_load_dwordx4 %12, %16, off offset:192 sc0 sc1\n\t"                 \
    "global_load_dwordx4 %13, %16, off offset:208 sc0 sc1\n\t"                 \
    "global_load_dwordx4 %14, %16, off offset:224 sc0 sc1\n\t"                 \
    "global_load_dwordx4 %15, %16, off offset:240 sc0 sc1\n\t"                 \
    "s_waitcnt vmcnt(0)"                                                       \
    : "=&v"(d[0]),"=&v"(d[1]),"=&v"(d[2]),"=&v"(d[3]),"=&v"(d[4]),"=&v"(d[5]), \
      "=&v"(d[6]),"=&v"(d[7]),"=&v"(d[8]),"=&v"(d[9]),"=&v"(d[10]),            \
      "=&v"(d[11]),"=&v"(d[12]),"=&v"(d[13]),"=&v"(d[14]),"=&v"(d[15])         \
    : "v"(base) : "memory")

// returning 8B swap (ack at coherence point) — tail only
__device__ __forceinline__ void swap_store8(void* p, u32x2 d) {
  u32x2 old;
  asm volatile("global_atomic_swap_x2 %0, %1, %2, off sc0 sc1\n\t"
               "s_waitcnt vmcnt(0)"
               : "=&v"(old) : "v"(p), "v"(d) : "memory");
}
__device__ __forceinline__ void bar_arrive(unsigned* bar, int l) {
  if (l == 0) {
    unsigned one = 1u;
    asm volatile("global_atomic_add %0, %1, off sc1" :: "v"(bar), "v"(one) : "memory");
  }
}
__device__ __forceinline__ void bar_wait(const unsigned* bar, unsigned tgt) {
  unsigned cur;
  do {
    asm volatile("global_load_dword %0, %1, off sc0 sc1\n\t"
                 "s_waitcnt vmcnt(0)"
                 : "=&v"(cur) : "v"(bar) : "memory");
  } while (cur < tgt);
}

// per-member flag: swap monotonic generation into a private 64B-spaced dword
// (no RMW contention, fire-and-forget)
__device__ __forceinline__ void arrive_flag(unsigned* base, int mem, int l,
                                            unsigned gen) {
  if (l == 0) {
    unsigned* p = base + (mem << 4);         // 64 B spacing
    asm volatile("global_atomic_swap %0, %1, off sc1"
                 :: "v"(p), "v"(gen) : "memory");
  }
}
// detect: lane l polls member (l&31)'s flag; all 32 flags must reach tgt
__device__ __forceinline__ void wait_flags(const unsigned* base, int l,
                                           unsigned tgt) {
  const unsigned* p = base + ((l & 31) << 4);
  unsigned f;
  do {
    asm volatile("global_load_dword %0, %1, off sc0 sc1\n\t"
                 "s_waitcnt vmcnt(0)"
                 : "=&v"(f) : "v"(p) : "memory");
  } while (!__all((int)(f >= tgt)));
}

// publish 4 gate values (bf16) of (row n, dims jb+kg*4..+4) held by lanes
// (n<8, kg) as tagged 8B packets: lane l' sends (row=l'&7, pair q=l'>>3).
__device__ __forceinline__ void publish(char* region, int m, int l,
                                        unsigned d0, unsigned d1, unsigned tag) {
  const int src = (((l & 7) + ((l >> 4) << 4)) << 2);   // source lane * 4
  const int p0 = __builtin_amdgcn_ds_bpermute(src, (int)d0);
  const int p1 = __builtin_amdgcn_ds_bpermute(src, (int)d1);
  u32x2 pkt;
  pkt[0] = ((l >> 3) & 1) ? (unsigned)p1 : (unsigned)p0;
  pkt[1] = tag;
  void* addr = region + (((u64)((l & 7)*256 + m*8 + (l >> 3))) << 3);
  asm volatile("global_atomic_swap_x2 %0, %1, off sc1"
               :: "v"(addr), "v"(pkt) : "memory");    // fire-and-forget
}

// post-detect tagged read: usually 1 round; retry if a packet trails its
// member's flag swap (different addresses, no ordering guarantee).
__device__ __forceinline__ void read_tagged(const char* re, int l, unsigned tag,
                                            u32x4* dd) {
  const char* b = re + (l << 4);
  int fut = 0;
  for (;;) {
    POLL16(dd, b, b + 4096, b + 8192, b + 12288);
    int ok = 1;
#pragma unroll
    for (int i = 0; i < 16; ++i) ok &= (int)((dd[i][1] == tag) & (dd[i][3] == tag));
    if (__all(ok)) return;
    if (++fut >= 8) __builtin_amdgcn_s_sleep(1);   // safety valve only
  }
}

// ---------------- prep ----------------
__global__ void prep_kernel(const int* __restrict__ X,
                            const float* __restrict__ Wr_w, const float* __restrict__ Wz_w,
                            const float* __restrict__ Wxh_w,
                            const float* __restrict__ Wr_b, const float* __restrict__ Ur_b,
                            const float* __restrict__ Wz_b, const float* __restrict__ Uz_b,
                            const float* __restrict__ Wxh_b, const float* __restrict__ Whh_b,
                            u16* __restrict__ Wcat, float* __restrict__ bias_cat,
                            int* __restrict__ lengths) {
  const int bid = blockIdx.x, tid = threadIdx.x;
  if (bid < 64) {
    __shared__ int sred[256];
    int s = 0;
    for (int i = tid; i < 2048; i += 256) s += (X[bid*2048 + i] != 0) ? 1 : 0;
    sred[tid] = s; __syncthreads();
    for (int st = 128; st > 0; st >>= 1) { if (tid < st) sred[tid] += sred[tid + st]; __syncthreads(); }
    if (tid == 0) lengths[bid] = sred[0];
  } else if (bid < 1600) {
    const int eid = (bid - 64)*256 + tid;      // < 393216
    const int e = eid & 7, lane = (eid >> 3) & 63, ks = (eid >> 9) & 7, s = eid >> 12;
    const int j = s*16 + (lane & 15);
    const int k = ks*32 + ((lane >> 4) << 3) + e;
    float v;
    if (j < 512)       v = Wr_w[j*256 + k];
    else if (j < 1024) v = Wz_w[(j-512)*256 + k];
    else               v = Wxh_w[(j-1024)*256 + k];
    Wcat[eid] = (u16)f2bf(v);
  } else {
    const int j = (bid - 1600)*256 + tid;
    if (j < 1536) {
      float v;
      if (j < 512)       v = Wr_b[j] + Ur_b[j];
      else if (j < 1024) v = Wz_b[j-512] + Uz_b[j-512];
      else               v = Wxh_b[j-1024] + Whh_b[j-1024];
      bias_cat[j] = v;
    }
  }
}

// ---------------- gemm_x ----------------
__launch_bounds__(256, 2)
__global__ void gemm_x_kernel(const int* __restrict__ X, const float* __restrict__ emb,
                              const u16* __restrict__ Wcat, const float* __restrict__ bias,
                              u16* __restrict__ xbuf, int t0) {
  __shared__ __align__(16) u16 Alds[32768];
  const int tile = blockIdx.x >> 1, jh = blockIdx.x & 1;
  const int tid = threadIdx.x;
  const int rbase = tile * 128;
#pragma unroll
  for (int c = 0; c < 16; ++c) {
    const int id = c * 256 + tid;
    const int row = id >> 5, k8 = id & 31;
    const int lr = rbase + row;
    const int b = lr & 63, t = t0 + (lr >> 6);
    int v = X[b*2048 + t];
    v = ((unsigned)v < 32000u) ? v : 0;
    s16x8 val = cvt8(emb + (long)v*256 + (k8 << 3));
    const int lane = (row & 15) | ((k8 & 3) << 4);
    const int slot = ((row >> 4)*8 + (k8 >> 2))*64 + lane;
    *(s16x8*)(&Alds[slot << 3]) = val;
  }
  __syncthreads();
  const int w = tid >> 6, l = tid & 63;
  s16x8 af[2][8];
#pragma unroll
  for (int m = 0; m < 2; ++m)
#pragma unroll
    for (int ks = 0; ks < 8; ++ks)
      af[m][ks] = *(const s16x8*)(&Alds[((((w*2+m)*8 + ks)*64) + l) << 3]);
  for (int s = jh*48; s < jh*48 + 48; ++s) {
    s16x8 bfr[8];
    const long wco = (long)s * 4096;
#pragma unroll
    for (int ks = 0; ks < 8; ++ks)
      bfr[ks] = *(const s16x8*)(Wcat + wco + ((ks*64 + l) << 3));
    f32x4 a0 = {0.f,0.f,0.f,0.f}, a1 = {0.f,0.f,0.f,0.f};
#pragma unroll
    for (int ks = 0; ks < 8; ++ks) {
      a0 = MFMA16(af[0][ks], bfr[ks], a0);
      a1 = MFMA16(af[1][ks], bfr[ks], a1);
    }
    const int j = s*16 + (l & 15);
    const float badd = bias[j];
    const int i0 = rbase + w*32 + ((l >> 4) << 2);
#pragma unroll
    for (int e = 0; e < 4; ++e) {
      xbuf[(long)(i0 + e)*1536 + j]      = (u16)f2bf(a0[e] + badd);
      xbuf[(long)(i0 + 16 + e)*1536 + j] = (u16)f2bf(a1[e] + badd);
    }
  }
}

// ---------------- scan ----------------
// 256 single-wave WGs. cluster cl = blockIdx&7 owns batch rows [8cl,8cl+8);
// member mem = blockIdx>>3 owns H-dims [16mem,16mem+16). Weights in LDS.
// Exchange region per cluster per parity: 8 rows x 256 slots x 8B = 16KB.
// Detection: per-member generation flags (advisory), tags gate correctness.
__launch_bounds__(64, 1)
__global__ void scan_kernel(const float* __restrict__ Ur_w, const float* __restrict__ Uz_w,
                            const float* __restrict__ Whh_w, const u16* __restrict__ xbuf,
                            const int* __restrict__ lengths, const float* __restrict__ V_w,
                            const float* __restrict__ V_b, char* __restrict__ hreg,
                            char* __restrict__ rreg, float* __restrict__ h_final,
                            unsigned* __restrict__ cnt, unsigned* __restrict__ pflag,
                            float* __restrict__ out,
                            int t0, int nsteps, int last) {
  __shared__ __align__(16) u16 Wlds[24576];  // 48 KiB: [mat(3)][ks(16)][lane(64)][e(8)]
  __shared__ __align__(16) u64 HLDS[2048];   // 16 KiB: [row(16)][dim-quad(128)]
  const int wg = blockIdx.x;
  const int cl = wg & 7, mem = wg >> 3;
  const int l = threadIdx.x;
  const int n = l & 15, kg = l >> 4;
  const int jb = mem * 16;
  const bool act = (n < 8);
  const int nc = act ? n : 7;
  const int rowb = cl * 8;

  // stage recurrent weights to LDS (A-frag order) and zero pad rows of HLDS
  {
    const float* Ws0 = Ur_w  + (jb + n)*512 + (kg << 3);
    const float* Ws1 = Uz_w  + (jb + n)*512 + (kg << 3);
    const float* Ws2 = Whh_w + (jb + n)*512 + (kg << 3);
#pragma unroll
    for (int ks = 0; ks < 16; ++ks) {
      *(s16x8*)(&Wlds[((     ks)*64 + l) << 3]) = cvt8(Ws0 + ks*32);
      *(s16x8*)(&Wlds[((16 + ks)*64 + l) << 3]) = cvt8(Ws1 + ks*32);
      *(s16x8*)(&Wlds[((32 + ks)*64 + l) << 3]) = cvt8(Ws2 + ks*32);
    }
#pragma unroll
    for (int i = 0; i < 16; ++i) HLDS[1024 + i*64 + l] = 0;   // pad rows 8..15
  }
  const int mylen = lengths[rowb + nc];
  const u16* xp = xbuf + (rowb + nc)*1536 + jb + (kg << 2);
  u16x4 pxr = *(const u16x4*)(xp);
  u16x4 pxz = *(const u16x4*)(xp + 512);
  u16x4 pxh = *(const u16x4*)(xp + 1024);

  char* hrc = hreg + ((u64)cl << 15);        // cluster regions (2 parities each)
  char* rrc = rreg + ((u64)cl << 15);
  unsigned* pf = pflag + cl*512;             // 32 member flags @ 64B spacing

  float h[4];
  if (t0 == 0) {
    h[0]=0.f; h[1]=0.f; h[2]=0.f; h[3]=0.f;
  } else {
    float4 hv = *(const float4*)(h_final + (rowb + nc)*512 + jb + (kg << 2));
    h[0]=hv.x; h[1]=hv.y; h[2]=hv.z; h[3]=hv.w;
  }

  for (int tl = 0; tl < nsteps; ++tl) {
    const int t = t0 + tl;
    const int par = t & 1;
    const u64 po  = (u64)par << 14;
    const u64 po2 = (u64)(par ^ 1) << 14;
    const unsigned tagA = (unsigned)t, tagB = (unsigned)(t + 1);
    u32x4 dd[16];
    // ---- phase A: wait h(t) (flags), read tagged, r-MFMA, publish r*h ----
    if (t > 0) wait_flags(pf, l, 2u*(unsigned)t);   // t=0: h(0) pre-zeroed, tag 0
    read_tagged(hrc + po, l, tagA, dd);
#pragma unroll
    for (int i = 0; i < 16; ++i)
      HLDS[(i*64 + l) ^ (((i >> 1) & 7) << 1)] = ((u64)dd[i][2] << 32) | (u64)dd[i][0];
    // r-MFMAs first, publish ASAP; z finished while packets are in flight
    f32x4 ar = {0.f,0.f,0.f,0.f};
#pragma unroll
    for (int ks = 0; ks < 16; ++ks) {
      const s16x8 hb = *(const s16x8*)((const char*)HLDS +
          (((n << 10) + ks*64 + (kg << 4)) ^ ((n & 7) << 4)));
      s16x8 w0 = *(const s16x8*)(&Wlds[(ks*64 + l) << 3]);
      ar = MFMA16(w0, hb, ar);
    }
    unsigned rd0, rd1;
    {
      unsigned short rb_[4];
#pragma unroll
      for (int e = 0; e < 4; ++e) {
        float rr = sigm(ar[e] + bf2f(pxr[e]));
        rb_[e]   = (unsigned short)f2bf(rr * h[e]);
      }
      rd0 = (unsigned)rb_[0] | ((unsigned)rb_[1] << 16);
      rd1 = (unsigned)rb_[2] | ((unsigned)rb_[3] << 16);
    }
    publish(rrc + po, mem, l, rd0, rd1, tagB);
    arrive_flag(pf, mem, l, 2u*(unsigned)t + 1u);
    // z-MFMAs + sigmoid while the rh exchange is in flight
    f32x4 az = {0.f,0.f,0.f,0.f};
#pragma unroll
    for (int ks = 0; ks < 16; ++ks) {
      const s16x8 hb = *(const s16x8*)((const char*)HLDS +
          (((n << 10) + ks*64 + (kg << 4)) ^ ((n & 7) << 4)));
      s16x8 w1 = *(const s16x8*)(&Wlds[((16 + ks)*64 + l) << 3]);
      az = MFMA16(w1, hb, az);
    }
    float zz[4];
#pragma unroll
    for (int e = 0; e < 4; ++e) zz[e] = sigm(az[e] + bf2f(pxz[e]));
    // prefetch next step's x while the exchange is in flight
    const int tn = (tl < nsteps-1) ? (tl + 1) : tl;
    const u16* xq = xp + (u64)tn*98304;
    u16x4 nxr = *(const u16x4*)(xq);
    u16x4 nxz = *(const u16x4*)(xq + 512);
    u16x4 nxh = *(const u16x4*)(xq + 1024);
    // ---- phase B: wait r*h (flags), read tagged, update, publish h(t+1) ----
    wait_flags(pf, l, 2u*(unsigned)t + 1u);
    read_tagged(rrc + po, l, tagB, dd);
#pragma unroll
    for (int i = 0; i < 16; ++i)
      HLDS[(i*64 + l) ^ (((i >> 1) & 7) << 1)] = ((u64)dd[i][2] << 32) | (u64)dd[i][0];
    f32x4 au = {0.f,0.f,0.f,0.f};
#pragma unroll
    for (int ks = 0; ks < 16; ++ks) {
      const s16x8 rb = *(const s16x8*)((const char*)HLDS +
          (((n << 10) + ks*64 + (kg << 4)) ^ ((n & 7) << 4)));
      s16x8 w2 = *(const s16x8*)(&Wlds[((32 + ks)*64 + l) << 3]);
      au = MFMA16(w2, rb, au);
    }
    unsigned hd0, hd1;
    {
      unsigned short hb_[4];
#pragma unroll
      for (int e = 0; e < 4; ++e) {
        float upd = ftanh(au[e] + bf2f(pxh[e]));
        float hn  = zz[e]*h[e] + (1.f - zz[e])*upd;
        h[e] = (t < mylen) ? hn : h[e];
        hb_[e] = (unsigned short)f2bf(h[e]);
      }
      hd0 = (unsigned)hb_[0] | ((unsigned)hb_[1] << 16);
      hd1 = (unsigned)hb_[2] | ((unsigned)hb_[3] << 16);
    }
    publish(hrc + po2, mem, l, hd0, hd1, tagB);
    arrive_flag(pf, mem, l, 2u*(unsigned)t + 2u);
    pxr = nxr; pxz = nxz; pxh = nxh;
  }

  if (!last) {
    // cross-launch handoff: kernel end writes back L2, plain store is fine
    if (act) {
      float4 hv; hv.x = h[0]; hv.y = h[1]; hv.z = h[2]; hv.w = h[3];
      *(float4*)(h_final + (rowb + n)*512 + jb + (kg << 2)) = hv;
    }
    return;
  }
  // last launch: publish fp32 h at device coherence point, cluster barrier, head
  if (act) {
    union { float f; unsigned u; } a0, a1, a2, a3;
    a0.f = h[0]; a1.f = h[1]; a2.f = h[2]; a3.f = h[3];
    float* hp = h_final + (rowb + n)*512 + jb + (kg << 2);
    u32x2 d0; d0[0] = a0.u; d0[1] = a1.u;
    u32x2 d1; d1[0] = a2.u; d1[1] = a3.u;
    swap_store8(hp, d0);
    swap_store8(hp + 2, d1);
  }
  unsigned* bar = cnt + cl*16;
  bar_arrive(bar, l);
  bar_wait(bar, 32u);
  // stage this cluster's 8 rows of h (16 KiB fp32) into LDS via coherent loads
  {
    f32x4 st[16];
    const float* hstage = h_final + rowb*512 + l*64;
    LOAD16_SC16(st, hstage);
    float* hlds = (float*)Wlds;
#pragma unroll
    for (int k = 0; k < 16; ++k) *(f32x4*)(&hlds[l*64 + k*4]) = st[k];
  }
  // out = tanh(hT @ V^T + V_b): WG covers its 16 dims x its 8 rows
  {
    const float* hlds = (const float*)Wlds;
    const int nn = l & 7, jo = l >> 3;
    const int j1 = jb + jo, j2 = jb + 8 + jo;
    const float* hrow = hlds + nn*512;
    const float* v1 = V_w + j1*512;
    const float* v2 = V_w + j2*512;
    float a1 = 0.f, a2 = 0.f;
    for (int k = 0; k < 512; k += 4) {
      float4 hv = *(const float4*)(hrow + k);
      float4 w1 = *(const float4*)(v1 + k);
      float4 w2 = *(const float4*)(v2 + k);
      a1 += hv.x*w1.x + hv.y*w1.y + hv.z*w1.z + hv.w*w1.w;
      a2 += hv.x*w2.x + hv.y*w2.y + hv.z*w2.z + hv.w*w2.w;
    }
    out[(rowb + nn)*512 + j1] = ftanh(a1 + V_b[j1]);
    out[(rowb + nn)*512 + j2] = ftanh(a2 + V_b[j2]);
  }
}

extern "C" void kernel_launch(void* const* d_in, const int* in_sizes, int n_in,
                              void* d_out, int out_size, void* d_ws, size_t ws_size,
                              hipStream_t stream) {
  const int*   X     = (const int*)d_in[0];
  const float* emb   = (const float*)d_in[1];
  const float* Wr_w  = (const float*)d_in[2];
  const float* Wr_b  = (const float*)d_in[3];
  const float* Ur_w  = (const float*)d_in[4];
  const float* Ur_b  = (const float*)d_in[5];
  const float* Wz_w  = (const float*)d_in[6];
  const float* Wz_b  = (const float*)d_in[7];
  const float* Uz_w  = (const float*)d_in[8];
  const float* Uz_b  = (const float*)d_in[9];
  const float* Wxh_w = (const float*)d_in[10];
  const float* Wxh_b = (const float*)d_in[11];
  const float* Whh_w = (const float*)d_in[12];
  const float* Whh_b = (const float*)d_in[13];
  const float* V_w   = (const float*)d_in[14];
  const float* V_b   = (const float*)d_in[15];
  (void)in_sizes; (void)n_in; (void)out_size;

  char* ws = (char*)d_ws;
  u16*      Wcat  = (u16*)ws;                     //     786,432 B
  float*    bias  = (float*)(ws + 786432L);       //       6,144 B
  int*      len   = (int*)(ws + 792576L);         //         256 B
  float*    hfin  = (float*)(ws + 792832L);       //     131,072 B
  unsigned* cnt   = (unsigned*)(ws + 923904L);    //         512 B (tail barrier)
  unsigned* pflag = (unsigned*)(ws + 924416L);    //      16,384 B (8c x 32 flags @64B)
  char*     hreg  = ws + 940800L;                 //     262,144 B (8c x 2p x 16KB)
  char*     rreg  = ws + 1202944L;                //     262,144 B
  u16*      xbuf  = (u16*)(ws + 1465088L);        // 402,653,184/NC B

  const long avail = (long)ws_size - 1465088L;
  int NC = 1;
  while (NC < 32 && (402653184L / NC) > avail) NC <<= 1;
  const int chunkT = 2048 / NC;

  // zero tail barrier, flags, exchange regions (gens/tags restart at 0)
  hipMemsetAsync(ws + 923904L, 0, 512 + 16384 + 2*262144L, stream);
  prep_kernel<<<1606, 256, 0, stream>>>(X, Wr_w, Wz_w, Wxh_w, Wr_b, Ur_b, Wz_b, Uz_b,
                                        Wxh_b, Whh_b, Wcat, bias, len);
  for (int c = 0; c < NC; ++c) {
    gemm_x_kernel<<<chunkT, 256, 0, stream>>>(X, emb, Wcat, bias, xbuf, c*chunkT);
    scan_kernel<<<256, 64, 0, stream>>>(Ur_w, Uz_w, Whh_w, xbuf, len, V_w, V_b,
                                        hreg, rreg, hfin, cnt, pflag, (float*)d_out,
                                        c*chunkT, chunkT, (c == NC-1) ? 1 : 0);
  }
}